// Round 1
// baseline (1769.346 us; speedup 1.0000x reference)
//
#include <hip/hip_runtime.h>
#include <hip/hip_bf16.h>

// Problem constants
constexpr int Bn = 16, Cn = 24, Sn = 128, En = 256, Hn = 8, Pn = 32;
constexpr int NROWS = Bn * Cn * Sn;            // 49152 rows of E
constexpr size_t NBUF = (size_t)Bn * Cn * Sn * En;  // 12,582,912 elems per buffer

using bf16 = __hip_bfloat16;

// ---------------------------------------------------------------------------
// Generic stride-parameterized GEMM:
//   for each joint c (blockIdx.z), rows m=(b,s) in [0,2048), cols n in [0,256):
//     O[b,c,s,n] = sum_e A[b,c,s,e] * W[c,e,n]   (+ optional bias / relu)
// A: element e contiguous; row addr = A + b*Ab + c*Ac + s*As.
// W addr = W + c*Wc + e*We + (n>>5)*Wnh + (n&31)*Wnp   (covers all weight layouts)
// O addr = O + b*Ob + c*Oc + s*Os + (n>>5)*Onh + (n&31)*Onp
// EPI: 0 = none, 1 = bias+relu, 2 = bias
// ---------------------------------------------------------------------------
template <typename AT, int EPI>
__global__ __launch_bounds__(256) void gemm_k(
    const AT* __restrict__ A, int Ab, int Ac, int As,
    const float* __restrict__ W, int Wc, int We, int Wnh, int Wnp,
    bf16* __restrict__ O, int Ob, int Oc, int Os, int Onh, int Onp,
    const float* __restrict__ bias)
{
    const int c  = blockIdx.z;
    const int mt = blockIdx.x;   // 32 tiles of 64 rows
    const int nt = blockIdx.y;   // 4 tiles of 64 cols

    __shared__ float Asm[64][17];
    __shared__ float Bsm[16][65];

    const int tid = threadIdx.x;
    const int tm = tid >> 4, tn = tid & 15;   // 16x16 thread grid, 4x4 micro-tile

    // A-load indices: each thread loads 4 consecutive k for one row
    const int lam = tid >> 2;         // 0..63
    const int lak = (tid & 3) * 4;    // 0,4,8,12
    // B-load indices: each thread loads 4 consecutive n for one k
    const int lbk = tid >> 4;         // 0..15
    const int lbn = (tid & 15) * 4;   // 0..60

    const int m = mt * 64 + lam;
    const int b = m >> 7, s = m & 127;
    const AT* arow = A + (size_t)b * Ab + (size_t)c * Ac + (size_t)s * As;
    const int nbase = nt * 64;

    float acc[4][4] = {};

    for (int k0 = 0; k0 < 256; k0 += 16) {
#pragma unroll
        for (int i = 0; i < 4; i++)
            Asm[lam][lak + i] = (float)arow[k0 + lak + i];
        const int e = k0 + lbk;
#pragma unroll
        for (int j = 0; j < 4; j++) {
            const int n = nbase + lbn + j;
            Bsm[lbk][lbn + j] =
                W[(size_t)c * Wc + (size_t)e * We + (size_t)(n >> 5) * Wnh + (n & 31) * Wnp];
        }
        __syncthreads();
#pragma unroll
        for (int kk = 0; kk < 16; kk++) {
            float av[4], bv[4];
#pragma unroll
            for (int i = 0; i < 4; i++) av[i] = Asm[tm * 4 + i][kk];
#pragma unroll
            for (int j = 0; j < 4; j++) bv[j] = Bsm[kk][tn * 4 + j];
#pragma unroll
            for (int i = 0; i < 4; i++)
#pragma unroll
                for (int j = 0; j < 4; j++) acc[i][j] += av[i] * bv[j];
        }
        __syncthreads();
    }

#pragma unroll
    for (int i = 0; i < 4; i++) {
        const int m2 = mt * 64 + tm * 4 + i;
        const int b2 = m2 >> 7, s2 = m2 & 127;
#pragma unroll
        for (int j = 0; j < 4; j++) {
            const int n = nbase + tn * 4 + j;
            float v = acc[i][j];
            if (EPI) {
                v += bias[c * 256 + n];
                if (EPI == 1) v = fmaxf(v, 0.f);
            }
            O[(size_t)b2 * Ob + (size_t)c * Oc + (size_t)s2 * Os +
              (size_t)(n >> 5) * Onh + (n & 31) * Onp] = __float2bfloat16(v);
        }
    }
}

// ---------------------------------------------------------------------------
// Spatial attention: one wave per (b,s,h). Q/K/V layout [B,S,H,C,P].
// scores over joints (C=24), softmax over d, o -> [B,C,S,E] at col h*32+p.
// ---------------------------------------------------------------------------
__global__ __launch_bounds__(64) void attn_spatial_k(
    const bf16* __restrict__ Q, const bf16* __restrict__ K,
    const bf16* __restrict__ V, bf16* __restrict__ O)
{
    const int id = blockIdx.x;
    const int h = id & 7;
    const int bs = id >> 3;
    const int s = bs & 127, b = bs >> 7;
    const size_t base = (((size_t)b * Sn + s) * Hn + h) * (Cn * Pn);

    __shared__ float qs[Cn][Pn + 1], ks[Cn][Pn + 1], vs[Cn][Pn + 1];
    __shared__ float as[Cn][Cn + 1];

    const int t = threadIdx.x;
    for (int i = t; i < Cn * Pn; i += 64) {
        const int cc = i >> 5, p = i & 31;
        qs[cc][p] = __bfloat162float(Q[base + i]);
        ks[cc][p] = __bfloat162float(K[base + i]);
        vs[cc][p] = __bfloat162float(V[base + i]);
    }
    __syncthreads();

    const float scale = 0.17677669529663687f;  // 1/sqrt(32)
    for (int i = t; i < Cn * Cn; i += 64) {
        const int cc = i / Cn, d = i % Cn;
        float sum = 0.f;
#pragma unroll
        for (int p = 0; p < Pn; p++) sum += qs[cc][p] * ks[d][p];
        as[cc][d] = sum * scale;
    }
    __syncthreads();

    if (t < Cn) {
        float mx = -1e30f;
        for (int d = 0; d < Cn; d++) mx = fmaxf(mx, as[t][d]);
        float sm = 0.f;
        for (int d = 0; d < Cn; d++) { const float e = expf(as[t][d] - mx); as[t][d] = e; sm += e; }
        const float inv = 1.f / sm;
        for (int d = 0; d < Cn; d++) as[t][d] *= inv;
    }
    __syncthreads();

    for (int i = t; i < Cn * Pn; i += 64) {
        const int cc = i >> 5, p = i & 31;
        float sum = 0.f;
#pragma unroll
        for (int d = 0; d < Cn; d++) sum += as[cc][d] * vs[d][p];
        O[((size_t)(b * Cn + cc) * Sn + s) * En + h * Pn + p] = __float2bfloat16(sum);
    }
}

// ---------------------------------------------------------------------------
// Temporal attention: one block (256 thr = 4 waves) per (b,h,c).
// Q/K/V layout [B,H,C,S,P]; wave handles one query row s at a time,
// softmax over t (S=128). Pitch-33 LDS avoids the stride-32 bank conflict.
// ---------------------------------------------------------------------------
__global__ __launch_bounds__(256) void attn_temporal_k(
    const bf16* __restrict__ Q, const bf16* __restrict__ K,
    const bf16* __restrict__ V, bf16* __restrict__ O)
{
    const int id = blockIdx.x;
    const int c = id % Cn;
    const int bh = id / Cn;
    const int h = bh % Hn, b = bh / Hn;
    const size_t base = ((size_t)(b * Hn + h) * Cn + c) * (Sn * Pn);

    __shared__ float qs[Sn * 33], ks[Sn * 33], vs[Sn * 33];
    __shared__ float aw[4][Sn];

    const int t = threadIdx.x;
    for (int i = t; i < Sn * Pn; i += 256) {
        const int r = i >> 5, p = i & 31;
        qs[r * 33 + p] = __bfloat162float(Q[base + i]);
        ks[r * 33 + p] = __bfloat162float(K[base + i]);
        vs[r * 33 + p] = __bfloat162float(V[base + i]);
    }
    __syncthreads();

    const int wave = t >> 6, lane = t & 63;
    const float scale = 0.17677669529663687f;

    for (int s = wave; s < Sn; s += 4) {
        const int t0 = lane, t1 = lane + 64;
        float sc0 = 0.f, sc1 = 0.f;
#pragma unroll
        for (int p = 0; p < Pn; p++) {
            const float qv = qs[s * 33 + p];
            sc0 += qv * ks[t0 * 33 + p];
            sc1 += qv * ks[t1 * 33 + p];
        }
        sc0 *= scale; sc1 *= scale;

        float mx = fmaxf(sc0, sc1);
        for (int d = 32; d; d >>= 1) mx = fmaxf(mx, __shfl_xor(mx, d));
        const float e0 = expf(sc0 - mx), e1 = expf(sc1 - mx);
        float sum = e0 + e1;
        for (int d = 32; d; d >>= 1) sum += __shfl_xor(sum, d);
        const float inv = 1.f / sum;
        aw[wave][t0] = e0 * inv;
        aw[wave][t1] = e1 * inv;
        // same-wave LDS write->read: program order within the wave

        const int p = lane & 31, half = lane >> 5;
        float acc = 0.f;
        const int tb = half * 64;
#pragma unroll 8
        for (int tt = tb; tt < tb + 64; tt++) acc += aw[wave][tt] * vs[tt * 33 + p];
        acc += __shfl_xor(acc, 32);
        if (lane < 32)
            O[((size_t)(b * Cn + c) * Sn + s) * En + h * Pn + p] = __float2bfloat16(acc);
    }
}

// ---------------------------------------------------------------------------
// attn_out = LN(x + spat) + LN(x + temp)   (one wave per row of E=256)
// ---------------------------------------------------------------------------
__global__ __launch_bounds__(256) void ln_combine_k(
    const float* __restrict__ x, const bf16* __restrict__ spat,
    const bf16* __restrict__ temp, const float* __restrict__ g,
    const float* __restrict__ beta, bf16* __restrict__ AO)
{
    const int row = blockIdx.x * 4 + (threadIdx.x >> 6);
    const int lane = threadIdx.x & 63;
    const size_t off = (size_t)row * En;

    float v1[4], v2[4];
    float s1 = 0, s2 = 0, q1 = 0, q2 = 0;
#pragma unroll
    for (int i = 0; i < 4; i++) {
        const int e = lane + i * 64;
        const float xv = x[off + e];
        const float a = xv + __bfloat162float(spat[off + e]);
        const float t = xv + __bfloat162float(temp[off + e]);
        v1[i] = a; v2[i] = t;
        s1 += a; s2 += t; q1 += a * a; q2 += t * t;
    }
    for (int d = 32; d; d >>= 1) {
        s1 += __shfl_xor(s1, d); s2 += __shfl_xor(s2, d);
        q1 += __shfl_xor(q1, d); q2 += __shfl_xor(q2, d);
    }
    const float mu1 = s1 / En, mu2 = s2 / En;
    const float r1 = rsqrtf(q1 / En - mu1 * mu1 + 1e-6f);
    const float r2 = rsqrtf(q2 / En - mu2 * mu2 + 1e-6f);
#pragma unroll
    for (int i = 0; i < 4; i++) {
        const int e = lane + i * 64;
        const float out = (v1[i] - mu1) * r1 * g[e] + beta[e] +
                          (v2[i] - mu2) * r2 * g[e] + beta[e];
        AO[off + e] = __float2bfloat16(out);
    }
}

// ---------------------------------------------------------------------------
// out = LN(attn_out + ff)  -> fp32 d_out
// ---------------------------------------------------------------------------
__global__ __launch_bounds__(256) void ln_final_k(
    const bf16* __restrict__ AO, const bf16* __restrict__ FF,
    const float* __restrict__ g, const float* __restrict__ beta,
    float* __restrict__ out)
{
    const int row = blockIdx.x * 4 + (threadIdx.x >> 6);
    const int lane = threadIdx.x & 63;
    const size_t off = (size_t)row * En;

    float v[4];
    float s = 0, q = 0;
#pragma unroll
    for (int i = 0; i < 4; i++) {
        const int e = lane + i * 64;
        const float a = __bfloat162float(AO[off + e]) + __bfloat162float(FF[off + e]);
        v[i] = a; s += a; q += a * a;
    }
    for (int d = 32; d; d >>= 1) { s += __shfl_xor(s, d); q += __shfl_xor(q, d); }
    const float mu = s / En;
    const float r = rsqrtf(q / En - mu * mu + 1e-6f);
#pragma unroll
    for (int i = 0; i < 4; i++) {
        const int e = lane + i * 64;
        out[off + e] = (v[i] - mu) * r * g[e] + beta[e];
    }
}

// ---------------------------------------------------------------------------
extern "C" void kernel_launch(void* const* d_in, const int* in_sizes, int n_in,
                              void* d_out, int out_size, void* d_ws, size_t ws_size,
                              hipStream_t stream)
{
    const float* x     = (const float*)d_in[0];
    const float* Wq_s  = (const float*)d_in[1];
    const float* Wk_s  = (const float*)d_in[2];
    const float* Wv_s  = (const float*)d_in[3];
    const float* Wo_s  = (const float*)d_in[4];
    const float* Wq_t  = (const float*)d_in[5];
    const float* Wk_t  = (const float*)d_in[6];
    const float* Wv_t  = (const float*)d_in[7];
    const float* Wo_t  = (const float*)d_in[8];
    const float* ln_g  = (const float*)d_in[9];
    const float* ln_b  = (const float*)d_in[10];
    const float* ff_w1 = (const float*)d_in[11];
    const float* ff_b1 = (const float*)d_in[12];
    const float* ff_w2 = (const float*)d_in[13];
    const float* ff_b2 = (const float*)d_in[14];
    float* out = (float*)d_out;

    bf16* wsb = (bf16*)d_ws;
    bf16* b0 = wsb;                 // 25.2 MB each; 5 buffers = 126 MB total
    bf16* b1 = wsb + NBUF;
    bf16* b2 = wsb + 2 * NBUF;
    bf16* b3 = wsb + 3 * NBUF;
    bf16* b4 = wsb + 4 * NBUF;

    const dim3 gg(32, 4, 24), gb(256);

    // strides (elements)
    // x / [B,C,S,E] buffers
    const int XAb = Cn * Sn * En, XAc = Sn * En, XAs = En;       // 786432,32768,256
    // Q/K/V spatial [B,S,H,C,P]
    const int QSb = Sn * Hn * Cn * Pn, QSs = Hn * Cn * Pn, QSh = Cn * Pn, QSc = Pn;
    // Q/K/V temporal [B,H,C,S,P]
    const int QTb = Hn * Cn * Sn * Pn, QTh = Cn * Sn * Pn, QTc = Sn * Pn, QTs = Pn;
    // [B,C,S,E] outputs
    const int OEb = XAb, OEc = XAc, OEs = XAs;

    // --- spatial q,k,v ---
    // q_s: W[h,c,p,e] -> c*P*E + h*C*P*E + p*E + e
    gemm_k<float, 0><<<gg, gb, 0, stream>>>(
        x, XAb, XAc, XAs, Wq_s, Pn * En, 1, Cn * Pn * En, En,
        b0, QSb, QSc, QSs, QSh, 1, nullptr);
    // k_s: W[h,e,p] -> h*E*P + e*P + p
    gemm_k<float, 0><<<gg, gb, 0, stream>>>(
        x, XAb, XAc, XAs, Wk_s, 0, Pn, En * Pn, 1,
        b1, QSb, QSc, QSs, QSh, 1, nullptr);
    gemm_k<float, 0><<<gg, gb, 0, stream>>>(
        x, XAb, XAc, XAs, Wv_s, 0, Pn, En * Pn, 1,
        b2, QSb, QSc, QSs, QSh, 1, nullptr);

    attn_spatial_k<<<Bn * Sn * Hn, 64, 0, stream>>>(b0, b1, b2, b3);

    // spat = o @ Wo_s : W[c,e,f]
    gemm_k<bf16, 0><<<gg, gb, 0, stream>>>(
        b3, XAb, XAc, XAs, Wo_s, En * En, En, 32, 1,
        b4, OEb, OEc, OEs, 32, 1, nullptr);

    // --- temporal q,k,v: W[h,c,e,p] -> h*C*E*P + c*E*P + e*P + p ---
    gemm_k<float, 0><<<gg, gb, 0, stream>>>(
        x, XAb, XAc, XAs, Wq_t, En * Pn, Pn, Cn * En * Pn, 1,
        b0, QTb, QTc, QTs, QTh, 1, nullptr);
    gemm_k<float, 0><<<gg, gb, 0, stream>>>(
        x, XAb, XAc, XAs, Wk_t, En * Pn, Pn, Cn * En * Pn, 1,
        b1, QTb, QTc, QTs, QTh, 1, nullptr);
    gemm_k<float, 0><<<gg, gb, 0, stream>>>(
        x, XAb, XAc, XAs, Wv_t, En * Pn, Pn, Cn * En * Pn, 1,
        b2, QTb, QTc, QTs, QTh, 1, nullptr);

    attn_temporal_k<<<Bn * Hn * Cn, 256, 0, stream>>>(b0, b1, b2, b3);

    // temp = o_t @ Wo_t  -> b0 (q_t dead)
    gemm_k<bf16, 0><<<gg, gb, 0, stream>>>(
        b3, XAb, XAc, XAs, Wo_t, En * En, En, 32, 1,
        b0, OEb, OEc, OEs, 32, 1, nullptr);

    // attn_out = LN(x+spat) + LN(x+temp) -> b1
    ln_combine_k<<<NROWS / 4, 256, 0, stream>>>(x, b4, b0, ln_g, ln_b, b1);

    // h = relu(attn_out @ ff_w1 + b1) -> b2
    gemm_k<bf16, 1><<<gg, gb, 0, stream>>>(
        b1, XAb, XAc, XAs, ff_w1, En * En, En, 32, 1,
        b2, OEb, OEc, OEs, 32, 1, ff_b1);
    // ff = h @ ff_w2 + b2 -> b3
    gemm_k<bf16, 2><<<gg, gb, 0, stream>>>(
        b2, XAb, XAc, XAs, ff_w2, En * En, En, 32, 1,
        b3, OEb, OEc, OEs, 32, 1, ff_b2);

    // out = LN(attn_out + ff)
    ln_final_k<<<NROWS / 4, 256, 0, stream>>>(b1, b3, ln_g, ln_b, out);
}

// Round 2
// 559.050 us; speedup vs baseline: 3.1649x; 3.1649x over previous
//
#include <hip/hip_runtime.h>
#include <hip/hip_bf16.h>

constexpr int Bn = 16, Cn = 24, Sn = 128, En = 256, Hn = 8, Pn = 32;
constexpr int NROWS = Bn * Cn * Sn;                  // 49152
constexpr size_t NBUF = (size_t)Bn * Cn * Sn * En;   // 12,582,912 elems

typedef __bf16 bf16_t;
typedef bf16_t bf16x8 __attribute__((ext_vector_type(8)));
typedef bf16_t bf16x4 __attribute__((ext_vector_type(4)));
typedef float f32x4 __attribute__((ext_vector_type(4)));

// global -> LDS direct 16B copy (dest = wave-uniform base + lane*16)
__device__ __forceinline__ void gl2lds16(const bf16_t* g, bf16_t* l) {
    typedef const __attribute__((address_space(1))) unsigned int* gp_t;
    typedef __attribute__((address_space(3))) unsigned int* lp_t;
    __builtin_amdgcn_global_load_lds((gp_t)(unsigned long long)g,
                                     (lp_t)(unsigned int)(unsigned long long)l,
                                     16, 0, 0);
}

// ---------------------------------------------------------------------------
// x fp32 -> bf16 (4 elems/thread)
// ---------------------------------------------------------------------------
__global__ __launch_bounds__(256) void conv_x_k(const float* __restrict__ x,
                                                bf16_t* __restrict__ xb) {
    const size_t i = ((size_t)blockIdx.x * 256 + threadIdx.x) * 4;
    const float4 v = *(const float4*)(x + i);
    bf16x4 o = {(bf16_t)v.x, (bf16_t)v.y, (bf16_t)v.z, (bf16_t)v.w};
    *(bf16x4*)(xb + i) = o;
}

// ---------------------------------------------------------------------------
// generic weight gather -> canonical bf16 [c][n][e] (e contiguous)
// Wb[(c*256+n)*256+e] = W[c*Sc + (n>>5)*Snh + (n&31)*Snp + e*Se]
// grid.x = Nc*256 (block per (c,n) row), 256 threads over e
// ---------------------------------------------------------------------------
__global__ __launch_bounds__(256) void conv_w_k(const float* __restrict__ W,
                                                bf16_t* __restrict__ Wb,
                                                int Sc, int Snh, int Snp, int Se) {
    const int n = blockIdx.x & 255, c = blockIdx.x >> 8;
    const int e = threadIdx.x;
    Wb[(size_t)blockIdx.x * 256 + e] =
        (bf16_t)W[(size_t)c * Sc + (size_t)(n >> 5) * Snh + (n & 31) * Snp + (size_t)e * Se];
}

// ---------------------------------------------------------------------------
// bf16 MFMA GEMM: per joint c (blockIdx.z), rows m=s (blockIdx.x = b),
// cols n (blockIdx.y = 128-col tile). BM=128,BN=128,BK=32, 4 waves (2x2).
// A: [b,c,s,:] k contiguous. B canonical [c][n][k] (Wc=0 for shared weights).
// O addr = b*Ob + c*Oc + s*Os + (n>>5)*Onh + (n&31)*Onp. EPI: 0/1(bias+relu)/2(bias)
// ---------------------------------------------------------------------------
template <int EPI>
__global__ __launch_bounds__(256) void gemm_mfma(
    const bf16_t* __restrict__ A, int Ab, int Ac, int As,
    const bf16_t* __restrict__ Wb, int Wc,
    bf16_t* __restrict__ O, int Ob, int Oc, int Os, int Onh, int Onp,
    const float* __restrict__ bias)
{
    const int b = blockIdx.x, nt = blockIdx.y, c = blockIdx.z;
    __shared__ bf16_t As_lds[128 * 32];
    __shared__ bf16_t Bs_lds[128 * 32];

    const int tid = threadIdx.x, wv = tid >> 6, ln = tid & 63;
    const int wm = (wv >> 1) * 64, wn = (wv & 1) * 64;
    const int lr = ln & 15, lk = (ln >> 4) * 8;

    const bf16_t* Abase = A + (size_t)b * Ab + (size_t)c * Ac;
    const bf16_t* Bbase = Wb + (size_t)c * Wc + (size_t)(nt * 128) * 256;

    f32x4 acc[4][4] = {};

    for (int k0 = 0; k0 < 256; k0 += 32) {
#pragma unroll
        for (int it = 0; it < 2; ++it) {
            const int cb = it * 256 + wv * 64;      // wave-uniform chunk base
            const int mc = cb + ln;
            const int row = mc >> 2, kc = (mc & 3) * 8;
            gl2lds16(Abase + (size_t)row * As + k0 + kc, &As_lds[cb * 8]);
            gl2lds16(Bbase + (size_t)row * 256 + k0 + kc, &Bs_lds[cb * 8]);
        }
        __syncthreads();   // drains vmcnt -> staged data visible

        bf16x8 af[4], bf[4];
#pragma unroll
        for (int i = 0; i < 4; ++i)
            af[i] = *(const bf16x8*)&As_lds[(wm + i * 16 + lr) * 32 + lk];
#pragma unroll
        for (int j = 0; j < 4; ++j)
            bf[j] = *(const bf16x8*)&Bs_lds[(wn + j * 16 + lr) * 32 + lk];
#pragma unroll
        for (int i = 0; i < 4; ++i)
#pragma unroll
            for (int j = 0; j < 4; ++j)
                acc[i][j] = __builtin_amdgcn_mfma_f32_16x16x32_bf16(af[i], bf[j], acc[i][j], 0, 0, 0);
        __syncthreads();   // done reading before next stage overwrites
    }

    // epilogue: C-layout col=lane&15, row=(lane>>4)*4+r
#pragma unroll
    for (int i = 0; i < 4; ++i) {
        const int s = wm + i * 16 + (ln >> 4) * 4;
#pragma unroll
        for (int j = 0; j < 4; ++j) {
            const int n = nt * 128 + wn + j * 16 + lr;
            const size_t obase = (size_t)b * Ob + (size_t)c * Oc +
                                 (size_t)(n >> 5) * Onh + (size_t)(n & 31) * Onp;
#pragma unroll
            for (int r = 0; r < 4; ++r) {
                float v = acc[i][j][r];
                if (EPI) {
                    v += bias[c * 256 + n];
                    if (EPI == 1) v = fmaxf(v, 0.f);
                }
                O[obase + (size_t)(s + r) * Os] = (bf16_t)v;
            }
        }
    }
}

// ---------------------------------------------------------------------------
// Spatial attention (unchanged structure): one wave per (b,s,h), [B,S,H,C,P]
// ---------------------------------------------------------------------------
__global__ __launch_bounds__(64) void attn_spatial_k(
    const bf16_t* __restrict__ Q, const bf16_t* __restrict__ K,
    const bf16_t* __restrict__ V, bf16_t* __restrict__ O)
{
    const int id = blockIdx.x;
    const int h = id & 7;
    const int bs = id >> 3;
    const int s = bs & 127, b = bs >> 7;
    const size_t base = (((size_t)b * Sn + s) * Hn + h) * (Cn * Pn);

    __shared__ float qs[Cn][Pn + 1], ks[Cn][Pn + 1], vs[Cn][Pn + 1];
    __shared__ float as[Cn][Cn + 1];

    const int t = threadIdx.x;
    for (int i = t; i < Cn * Pn; i += 64) {
        const int cc = i >> 5, p = i & 31;
        qs[cc][p] = (float)Q[base + i];
        ks[cc][p] = (float)K[base + i];
        vs[cc][p] = (float)V[base + i];
    }
    __syncthreads();

    const float scale = 0.17677669529663687f;
    for (int i = t; i < Cn * Cn; i += 64) {
        const int cc = i / Cn, d = i % Cn;
        float sum = 0.f;
#pragma unroll
        for (int p = 0; p < Pn; p++) sum += qs[cc][p] * ks[d][p];
        as[cc][d] = sum * scale;
    }
    __syncthreads();

    if (t < Cn) {
        float mx = -1e30f;
        for (int d = 0; d < Cn; d++) mx = fmaxf(mx, as[t][d]);
        float sm = 0.f;
        for (int d = 0; d < Cn; d++) { const float e = __expf(as[t][d] - mx); as[t][d] = e; sm += e; }
        const float inv = 1.f / sm;
        for (int d = 0; d < Cn; d++) as[t][d] *= inv;
    }
    __syncthreads();

    for (int i = t; i < Cn * Pn; i += 64) {
        const int cc = i >> 5, p = i & 31;
        float sum = 0.f;
#pragma unroll
        for (int d = 0; d < Cn; d++) sum += as[cc][d] * vs[d][p];
        O[((size_t)(b * Cn + cc) * Sn + s) * En + h * Pn + p] = (bf16_t)sum;
    }
}

// ---------------------------------------------------------------------------
// Temporal attention, MFMA. One block (4 waves) per (b,h,c).
// Q,K: [b,h,c,s,p] (k=p contiguous). Vt: [b,h,c,p,s] (V pre-transposed, k=s).
// Wave w owns query rows [32w,32w+32). QK^T -> reg softmax -> P via LDS -> PV.
// ---------------------------------------------------------------------------
__global__ __launch_bounds__(256) void attn_temporal_mfma(
    const bf16_t* __restrict__ Q, const bf16_t* __restrict__ K,
    const bf16_t* __restrict__ Vt, bf16_t* __restrict__ O)
{
    const int c = blockIdx.x, h = blockIdx.y, b = blockIdx.z;
    const size_t base = ((size_t)(b * Hn + h) * Cn + c) * (Sn * Pn);

    __shared__ bf16_t Qs[128 * 32];        // [s][p]
    __shared__ bf16_t Ks[128 * 32];        // [t][p]
    __shared__ bf16_t Vs[32 * 136];        // [p][t], pitch 136
    __shared__ bf16_t Ps[128 * 136];       // [s][t], pitch 136

    const int tid = threadIdx.x, wv = tid >> 6, ln = tid & 63;
    const int lr = ln & 15, lk = (ln >> 4) * 8;

#pragma unroll
    for (int it = 0; it < 2; ++it) {
        const int cb = it * 256 + wv * 64;
        const int mc = cb + ln;
        const int row = mc >> 2, kc = (mc & 3) * 8;
        gl2lds16(Q + base + row * 32 + kc, &Qs[cb * 8]);
        gl2lds16(K + base + row * 32 + kc, &Ks[cb * 8]);
    }
#pragma unroll
    for (int it = 0; it < 2; ++it) {
        const int mc = it * 256 + tid;     // p = mc>>4, s-chunk = (mc&15)*8
        const int p = mc >> 4, sc = (mc & 15) * 8;
        bf16x8 v = *(const bf16x8*)(Vt + base + p * 128 + sc);
        *(bf16x8*)&Vs[p * 136 + sc] = v;
    }
    __syncthreads();

    // --- QK^T: rows r0..r0+31, all 128 cols ---
    const int r0 = wv * 32;
    bf16x8 aq0 = *(const bf16x8*)&Qs[(r0 + lr) * 32 + lk];
    bf16x8 aq1 = *(const bf16x8*)&Qs[(r0 + 16 + lr) * 32 + lk];
    f32x4 sc_[2][8];
    const f32x4 zz = {0.f, 0.f, 0.f, 0.f};
#pragma unroll
    for (int j = 0; j < 8; ++j) {
        bf16x8 bk = *(const bf16x8*)&Ks[(j * 16 + lr) * 32 + lk];
        sc_[0][j] = __builtin_amdgcn_mfma_f32_16x16x32_bf16(aq0, bk, zz, 0, 0, 0);
        sc_[1][j] = __builtin_amdgcn_mfma_f32_16x16x32_bf16(aq1, bk, zz, 0, 0, 0);
    }

    // --- softmax over cols; row = r0+16i+(ln>>4)*4+r, col = 16j+(ln&15) ---
    const float scale = 0.17677669529663687f;
#pragma unroll
    for (int i = 0; i < 2; ++i) {
        float mx[4], sm[4];
#pragma unroll
        for (int r = 0; r < 4; ++r) {
            float m = sc_[i][0][r];
#pragma unroll
            for (int j = 1; j < 8; ++j) m = fmaxf(m, sc_[i][j][r]);
            mx[r] = m;
        }
#pragma unroll
        for (int d = 1; d < 16; d <<= 1)
#pragma unroll
            for (int r = 0; r < 4; ++r) mx[r] = fmaxf(mx[r], __shfl_xor(mx[r], d));
#pragma unroll
        for (int r = 0; r < 4; ++r) sm[r] = 0.f;
#pragma unroll
        for (int j = 0; j < 8; ++j)
#pragma unroll
            for (int r = 0; r < 4; ++r) {
                const float e = __expf((sc_[i][j][r] - mx[r]) * scale);
                sc_[i][j][r] = e; sm[r] += e;
            }
#pragma unroll
        for (int d = 1; d < 16; d <<= 1)
#pragma unroll
            for (int r = 0; r < 4; ++r) sm[r] += __shfl_xor(sm[r], d);
        float inv[4];
#pragma unroll
        for (int r = 0; r < 4; ++r) inv[r] = 1.f / sm[r];
        const int rb = r0 + i * 16 + (ln >> 4) * 4;
#pragma unroll
        for (int j = 0; j < 8; ++j)
#pragma unroll
            for (int r = 0; r < 4; ++r)
                Ps[(rb + r) * 136 + j * 16 + lr] = (bf16_t)(sc_[i][j][r] * inv[r]);
    }
    __syncthreads();

    // --- PV: O[rows r0..r0+31][p 0..31] ---
    f32x4 o[2][2] = {};
#pragma unroll
    for (int kk = 0; kk < 4; ++kk) {
        bf16x8 ap0 = *(const bf16x8*)&Ps[(r0 + lr) * 136 + kk * 32 + lk];
        bf16x8 ap1 = *(const bf16x8*)&Ps[(r0 + 16 + lr) * 136 + kk * 32 + lk];
        bf16x8 bv0 = *(const bf16x8*)&Vs[lr * 136 + kk * 32 + lk];
        bf16x8 bv1 = *(const bf16x8*)&Vs[(16 + lr) * 136 + kk * 32 + lk];
        o[0][0] = __builtin_amdgcn_mfma_f32_16x16x32_bf16(ap0, bv0, o[0][0], 0, 0, 0);
        o[0][1] = __builtin_amdgcn_mfma_f32_16x16x32_bf16(ap0, bv1, o[0][1], 0, 0, 0);
        o[1][0] = __builtin_amdgcn_mfma_f32_16x16x32_bf16(ap1, bv0, o[1][0], 0, 0, 0);
        o[1][1] = __builtin_amdgcn_mfma_f32_16x16x32_bf16(ap1, bv1, o[1][1], 0, 0, 0);
    }

#pragma unroll
    for (int i = 0; i < 2; ++i) {
        const int sb = r0 + i * 16 + (ln >> 4) * 4;
#pragma unroll
        for (int j = 0; j < 2; ++j) {
            const int p = h * 32 + j * 16 + lr;
#pragma unroll
            for (int r = 0; r < 4; ++r)
                O[((size_t)(b * Cn + c) * Sn + (sb + r)) * En + p] = (bf16_t)o[i][j][r];
        }
    }
}

// ---------------------------------------------------------------------------
// attn_out = LN(x + spat) + LN(x + temp)
// ---------------------------------------------------------------------------
__global__ __launch_bounds__(256) void ln_combine_k(
    const float* __restrict__ x, const bf16_t* __restrict__ spat,
    const bf16_t* __restrict__ temp, const float* __restrict__ g,
    const float* __restrict__ beta, bf16_t* __restrict__ AO)
{
    const int row = blockIdx.x * 4 + (threadIdx.x >> 6);
    const int lane = threadIdx.x & 63;
    const size_t off = (size_t)row * En;

    float v1[4], v2[4];
    float s1 = 0, s2 = 0, q1 = 0, q2 = 0;
#pragma unroll
    for (int i = 0; i < 4; i++) {
        const int e = lane + i * 64;
        const float xv = x[off + e];
        const float a = xv + (float)spat[off + e];
        const float t = xv + (float)temp[off + e];
        v1[i] = a; v2[i] = t;
        s1 += a; s2 += t; q1 += a * a; q2 += t * t;
    }
    for (int d = 32; d; d >>= 1) {
        s1 += __shfl_xor(s1, d); s2 += __shfl_xor(s2, d);
        q1 += __shfl_xor(q1, d); q2 += __shfl_xor(q2, d);
    }
    const float mu1 = s1 / En, mu2 = s2 / En;
    const float r1 = rsqrtf(q1 / En - mu1 * mu1 + 1e-6f);
    const float r2 = rsqrtf(q2 / En - mu2 * mu2 + 1e-6f);
#pragma unroll
    for (int i = 0; i < 4; i++) {
        const int e = lane + i * 64;
        const float out = (v1[i] - mu1) * r1 * g[e] + beta[e] +
                          (v2[i] - mu2) * r2 * g[e] + beta[e];
        AO[off + e] = (bf16_t)out;
    }
}

__global__ __launch_bounds__(256) void ln_final_k(
    const bf16_t* __restrict__ AO, const bf16_t* __restrict__ FF,
    const float* __restrict__ g, const float* __restrict__ beta,
    float* __restrict__ out)
{
    const int row = blockIdx.x * 4 + (threadIdx.x >> 6);
    const int lane = threadIdx.x & 63;
    const size_t off = (size_t)row * En;

    float v[4];
    float s = 0, q = 0;
#pragma unroll
    for (int i = 0; i < 4; i++) {
        const int e = lane + i * 64;
        const float a = (float)AO[off + e] + (float)FF[off + e];
        v[i] = a; s += a; q += a * a;
    }
    for (int d = 32; d; d >>= 1) { s += __shfl_xor(s, d); q += __shfl_xor(q, d); }
    const float mu = s / En;
    const float r = rsqrtf(q / En - mu * mu + 1e-6f);
#pragma unroll
    for (int i = 0; i < 4; i++) {
        const int e = lane + i * 64;
        out[off + e] = (v[i] - mu) * r * g[e] + beta[e];
    }
}

// ---------------------------------------------------------------------------
extern "C" void kernel_launch(void* const* d_in, const int* in_sizes, int n_in,
                              void* d_out, int out_size, void* d_ws, size_t ws_size,
                              hipStream_t stream)
{
    const float* x     = (const float*)d_in[0];
    const float* Wq_s  = (const float*)d_in[1];
    const float* Wk_s  = (const float*)d_in[2];
    const float* Wv_s  = (const float*)d_in[3];
    const float* Wo_s  = (const float*)d_in[4];
    const float* Wq_t  = (const float*)d_in[5];
    const float* Wk_t  = (const float*)d_in[6];
    const float* Wv_t  = (const float*)d_in[7];
    const float* Wo_t  = (const float*)d_in[8];
    const float* ln_g  = (const float*)d_in[9];
    const float* ln_b  = (const float*)d_in[10];
    const float* ff_w1 = (const float*)d_in[11];
    const float* ff_b1 = (const float*)d_in[12];
    const float* ff_w2 = (const float*)d_in[13];
    const float* ff_b2 = (const float*)d_in[14];
    float* out = (float*)d_out;

    // ws: the 5 proven 25.2MB bf16 buffers
    bf16_t* wsb = (bf16_t*)d_ws;
    bf16_t* b0 = wsb;
    bf16_t* b1 = wsb + NBUF;
    bf16_t* b2 = wsb + 2 * NBUF;
    bf16_t* b3 = wsb + 3 * NBUF;
    bf16_t* b4 = wsb + 4 * NBUF;

    // d_out doubles as scratch until ln_final overwrites it:
    //   xb (NBUF bf16) + 8 big canonical weights (8 * 1572864 bf16) = exactly out bytes
    bf16_t* xb = (bf16_t*)d_out;
    bf16_t* wb = xb + NBUF;
    const size_t WSLOT = (size_t)Cn * 256 * 256;   // 1,572,864
    bf16_t* w_qs = wb + 0 * WSLOT;
    bf16_t* w_os = wb + 1 * WSLOT;
    bf16_t* w_qt = wb + 2 * WSLOT;
    bf16_t* w_kt = wb + 3 * WSLOT;
    bf16_t* w_vt = wb + 4 * WSLOT;
    bf16_t* w_ot = wb + 5 * WSLOT;
    bf16_t* w_f1 = wb + 6 * WSLOT;
    bf16_t* w_f2 = wb + 7 * WSLOT;
    // small shared k/v spatial weights at the tail of b4 (b4 first written by
    // the Wo_s GEMM, which runs after these weights are dead)
    bf16_t* w_ks = b4 + NBUF - 2 * 65536;
    bf16_t* w_vs = b4 + NBUF - 65536;

    // strides
    const int XAb = Cn * Sn * En, XAc = Sn * En, XAs = En;               // std [B,C,S,E]
    const int QSb = Sn * Hn * Cn * Pn, QSs = Hn * Cn * Pn, QSh = Cn * Pn, QSc = Pn; // [B,S,H,C,P]
    const int QTb = Hn * Cn * Sn * Pn, QTh = Cn * Sn * Pn, QTc = Sn * Pn, QTs = Pn; // [B,H,C,S,P]

    // --- conversions ---
    conv_x_k<<<NBUF / 1024, 256, 0, stream>>>(x, xb);
    conv_w_k<<<6144, 256, 0, stream>>>(Wq_s, w_qs, Pn * En, Cn * Pn * En, En, 1);
    conv_w_k<<<256,  256, 0, stream>>>(Wk_s, w_ks, 0, En * Pn, 1, Pn);
    conv_w_k<<<256,  256, 0, stream>>>(Wv_s, w_vs, 0, En * Pn, 1, Pn);
    conv_w_k<<<6144, 256, 0, stream>>>(Wo_s, w_os, En * En, 32, 1, En);
    conv_w_k<<<6144, 256, 0, stream>>>(Wq_t, w_qt, En * Pn, Cn * En * Pn, 1, Pn);
    conv_w_k<<<6144, 256, 0, stream>>>(Wk_t, w_kt, En * Pn, Cn * En * Pn, 1, Pn);
    conv_w_k<<<6144, 256, 0, stream>>>(Wv_t, w_vt, En * Pn, Cn * En * Pn, 1, Pn);
    conv_w_k<<<6144, 256, 0, stream>>>(Wo_t, w_ot, En * En, 32, 1, En);
    conv_w_k<<<6144, 256, 0, stream>>>(ff_w1, w_f1, En * En, 32, 1, En);
    conv_w_k<<<6144, 256, 0, stream>>>(ff_w2, w_f2, En * En, 32, 1, En);

    const dim3 gg(16, 2, 24), gb(256);
    const int WCP = 256 * 256;   // per-c weight stride

    // --- spatial branch ---
    gemm_mfma<0><<<gg, gb, 0, stream>>>(xb, XAb, XAc, XAs, w_qs, WCP,
        b0, QSb, QSc, QSs, QSh, 1, nullptr);
    gemm_mfma<0><<<gg, gb, 0, stream>>>(xb, XAb, XAc, XAs, w_ks, 0,
        b1, QSb, QSc, QSs, QSh, 1, nullptr);
    gemm_mfma<0><<<gg, gb, 0, stream>>>(xb, XAb, XAc, XAs, w_vs, 0,
        b2, QSb, QSc, QSs, QSh, 1, nullptr);
    attn_spatial_k<<<Bn * Sn * Hn, 64, 0, stream>>>(b0, b1, b2, b3);
    gemm_mfma<0><<<gg, gb, 0, stream>>>(b3, XAb, XAc, XAs, w_os, WCP,
        b4, XAb, XAc, XAs, 32, 1, nullptr);

    // --- temporal branch (v projected directly to V^T [b,h,c,p,s]) ---
    gemm_mfma<0><<<gg, gb, 0, stream>>>(xb, XAb, XAc, XAs, w_qt, WCP,
        b0, QTb, QTc, QTs, QTh, 1, nullptr);
    gemm_mfma<0><<<gg, gb, 0, stream>>>(xb, XAb, XAc, XAs, w_kt, WCP,
        b1, QTb, QTc, QTs, QTh, 1, nullptr);
    gemm_mfma<0><<<gg, gb, 0, stream>>>(xb, XAb, XAc, XAs, w_vt, WCP,
        b2, QTb, QTc, 1, QTh, Sn, nullptr);
    attn_temporal_mfma<<<dim3(24, 8, 16), 256, 0, stream>>>(b0, b1, b2, b3);
    gemm_mfma<0><<<gg, gb, 0, stream>>>(b3, XAb, XAc, XAs, w_ot, WCP,
        b0, XAb, XAc, XAs, 32, 1, nullptr);

    // --- combine + FF + final LN ---
    ln_combine_k<<<NROWS / 4, 256, 0, stream>>>(x, b4, b0, ln_g, ln_b, b1);
    gemm_mfma<1><<<gg, gb, 0, stream>>>(b1, XAb, XAc, XAs, w_f1, WCP,
        b2, XAb, XAc, XAs, 32, 1, ff_b1);
    gemm_mfma<2><<<gg, gb, 0, stream>>>(b2, XAb, XAc, XAs, w_f2, WCP,
        b3, XAb, XAc, XAs, 32, 1, ff_b2);
    ln_final_k<<<NROWS / 4, 256, 0, stream>>>(b1, b3, ln_g, ln_b, out);
}

// Round 3
// 529.314 us; speedup vs baseline: 3.3427x; 1.0562x over previous
//
#include <hip/hip_runtime.h>
#include <hip/hip_bf16.h>

constexpr int Bn = 16, Cn = 24, Sn = 128, En = 256, Hn = 8, Pn = 32;
constexpr int NROWS = Bn * Cn * Sn;                  // 49152
constexpr size_t NBUF = (size_t)Bn * Cn * Sn * En;   // 12,582,912 elems
constexpr size_t WSLOT = (size_t)Cn * 256 * 256;     // 1,572,864

typedef __bf16 bf16_t;
typedef bf16_t bf16x8 __attribute__((ext_vector_type(8)));
typedef bf16_t bf16x4 __attribute__((ext_vector_type(4)));
typedef float f32x4 __attribute__((ext_vector_type(4)));

// global -> LDS direct 16B copy (dest = wave-uniform base + lane*16)
__device__ __forceinline__ void gl2lds16(const bf16_t* g, bf16_t* l) {
    typedef const __attribute__((address_space(1))) unsigned int* gp_t;
    typedef __attribute__((address_space(3))) unsigned int* lp_t;
    __builtin_amdgcn_global_load_lds((gp_t)(unsigned long long)g,
                                     (lp_t)(unsigned int)(unsigned long long)l,
                                     16, 0, 0);
}

// ---------------------------------------------------------------------------
// x fp32 -> bf16
// ---------------------------------------------------------------------------
__global__ __launch_bounds__(256) void conv_x_k(const float* __restrict__ x,
                                                bf16_t* __restrict__ xb) {
    const size_t i = ((size_t)blockIdx.x * 256 + threadIdx.x) * 4;
    const float4 v = *(const float4*)(x + i);
    bf16x4 o = {(bf16_t)v.x, (bf16_t)v.y, (bf16_t)v.z, (bf16_t)v.w};
    *(bf16x4*)(xb + i) = o;
}

// ---------------------------------------------------------------------------
// fused weight gather -> canonical bf16 [slot][c][n][e]; blockIdx.y = slot
// ---------------------------------------------------------------------------
struct CDesc { const float* W; int Sc, Snh, Snp, Se; };

__global__ __launch_bounds__(256) void conv_w8_k(
    CDesc d0, CDesc d1, CDesc d2, CDesc d3, CDesc d4, CDesc d5, CDesc d6, CDesc d7,
    bf16_t* __restrict__ out)
{
    CDesc d;
    switch (blockIdx.y) {
        case 0: d = d0; break; case 1: d = d1; break;
        case 2: d = d2; break; case 3: d = d3; break;
        case 4: d = d4; break; case 5: d = d5; break;
        case 6: d = d6; break; default: d = d7; break;
    }
    const int n = blockIdx.x & 255, c = blockIdx.x >> 8;
    const int e = threadIdx.x;
    out[(size_t)blockIdx.y * WSLOT + (size_t)blockIdx.x * 256 + e] =
        (bf16_t)d.W[(size_t)c * d.Sc + (size_t)(n >> 5) * d.Snh + (n & 31) * d.Snp +
                    (size_t)e * d.Se];
}

// small shared spatial k/v weights
__global__ __launch_bounds__(256) void conv_w_k(const float* __restrict__ W,
                                                bf16_t* __restrict__ Wb,
                                                int Sc, int Snh, int Snp, int Se) {
    const int n = blockIdx.x & 255, c = blockIdx.x >> 8;
    const int e = threadIdx.x;
    Wb[(size_t)blockIdx.x * 256 + e] =
        (bf16_t)W[(size_t)c * Sc + (size_t)(n >> 5) * Snh + (n & 31) * Snp + (size_t)e * Se];
}

// ---------------------------------------------------------------------------
// bf16 MFMA GEMM, up to 3 fused projections sharing A.
// NP=1: grid.y = 2 n-tiles of g0. NP=3: grid.y = 6, proj = y>>1, tile = y&1.
// B canonical [c][n][k] (Wc=0 for c-shared weights).
// O addr = b*Ob + c*Oc + s*Os + (n>>5)*Onh + (n&31)*Onp. EPI: 0/1(bias+relu)/2(bias)
// ---------------------------------------------------------------------------
struct GDesc { const bf16_t* W; bf16_t* O; int Wc, Ob, Oc, Os, Onh, Onp; };

template <int NP, int EPI>
__global__ __launch_bounds__(256) void gemm_mfma(
    const bf16_t* __restrict__ A, int Ab, int Ac, int As,
    GDesc g0, GDesc g1, GDesc g2, const float* __restrict__ bias)
{
    const int b = blockIdx.x, c = blockIdx.z;
    const int proj = (NP == 1) ? 0 : ((int)blockIdx.y >> 1);
    const int nt = (NP == 1) ? (int)blockIdx.y : ((int)blockIdx.y & 1);
    GDesc g = (proj == 0) ? g0 : (proj == 1) ? g1 : g2;

    __shared__ bf16_t As_lds[128 * 32];
    __shared__ bf16_t Bs_lds[128 * 32];

    const int tid = threadIdx.x, wv = tid >> 6, ln = tid & 63;
    const int wm = (wv >> 1) * 64, wn = (wv & 1) * 64;
    const int lr = ln & 15, lk = (ln >> 4) * 8;

    const bf16_t* Abase = A + (size_t)b * Ab + (size_t)c * Ac;
    const bf16_t* Bbase = g.W + (size_t)c * g.Wc + (size_t)(nt * 128) * 256;

    f32x4 acc[4][4] = {};

    for (int k0 = 0; k0 < 256; k0 += 32) {
#pragma unroll
        for (int it = 0; it < 2; ++it) {
            const int cb = it * 256 + wv * 64;      // wave-uniform chunk base
            const int mc = cb + ln;
            const int row = mc >> 2, kc = (mc & 3) * 8;
            gl2lds16(Abase + (size_t)row * As + k0 + kc, &As_lds[cb * 8]);
            gl2lds16(Bbase + (size_t)row * 256 + k0 + kc, &Bs_lds[cb * 8]);
        }
        __syncthreads();

        bf16x8 af[4], bfr[4];
#pragma unroll
        for (int i = 0; i < 4; ++i)
            af[i] = *(const bf16x8*)&As_lds[(wm + i * 16 + lr) * 32 + lk];
#pragma unroll
        for (int j = 0; j < 4; ++j)
            bfr[j] = *(const bf16x8*)&Bs_lds[(wn + j * 16 + lr) * 32 + lk];
#pragma unroll
        for (int i = 0; i < 4; ++i)
#pragma unroll
            for (int j = 0; j < 4; ++j)
                acc[i][j] = __builtin_amdgcn_mfma_f32_16x16x32_bf16(af[i], bfr[j], acc[i][j], 0, 0, 0);
        __syncthreads();
    }

#pragma unroll
    for (int i = 0; i < 4; ++i) {
        const int s = wm + i * 16 + (ln >> 4) * 4;
#pragma unroll
        for (int j = 0; j < 4; ++j) {
            const int n = nt * 128 + wn + j * 16 + lr;
            const size_t obase = (size_t)b * g.Ob + (size_t)c * g.Oc +
                                 (size_t)(n >> 5) * g.Onh + (size_t)(n & 31) * g.Onp;
#pragma unroll
            for (int r = 0; r < 4; ++r) {
                float v = acc[i][j][r];
                if (EPI) {
                    v += bias[c * 256 + n];
                    if (EPI == 1) v = fmaxf(v, 0.f);
                }
                g.O[obase + (size_t)(s + r) * g.Os] = (bf16_t)v;
            }
        }
    }
}

// ---------------------------------------------------------------------------
// Spatial attention, MFMA, one wave per (b,s,h). 24x24 attention padded to 32.
// Q,K: [b,s,h,c,p] (k=p contiguous). Vt: [b,s,h,p,c] (k=c contiguous).
// Fragments load DIRECTLY from global (the frag pattern is a permutation of a
// contiguous wave read). Only P round-trips through per-wave LDS.
// Cols d>=24 masked to -3e38 -> P cols 24..31 are exact zeros, so garbage V
// k-columns are annihilated; rows c>=24 are never written.
// ---------------------------------------------------------------------------
__global__ __launch_bounds__(256) void attn_spatial_mfma(
    const bf16_t* __restrict__ Q, const bf16_t* __restrict__ K,
    const bf16_t* __restrict__ Vt, bf16_t* __restrict__ O)
{
    __shared__ bf16_t Ps[4][32 * 40];   // per-wave, pitch 40 (80B, 16B-aligned)

    const int tid = threadIdx.x, wv = tid >> 6, ln = tid & 63;
    const int lr = ln & 15, hi = ln >> 4, lk = hi * 8;

    const int bsh = blockIdx.x * 4 + wv;
    const int h = bsh & 7, s = (bsh >> 3) & 127, b = bsh >> 10;
    const size_t qb = (size_t)bsh * (Cn * Pn);   // 768 elems per unit

    // --- QK^T: 4 direct global frag loads + 4 MFMAs ---
    bf16x8 aq0 = *(const bf16x8*)(Q + qb + lr * 32 + lk);
    bf16x8 aq1 = *(const bf16x8*)(Q + qb + (16 + lr) * 32 + lk);
    bf16x8 bk0 = *(const bf16x8*)(K + qb + lr * 32 + lk);
    bf16x8 bk1 = *(const bf16x8*)(K + qb + (16 + lr) * 32 + lk);
    const f32x4 zz = {0.f, 0.f, 0.f, 0.f};
    f32x4 sc[2][2];
    sc[0][0] = __builtin_amdgcn_mfma_f32_16x16x32_bf16(aq0, bk0, zz, 0, 0, 0);
    sc[0][1] = __builtin_amdgcn_mfma_f32_16x16x32_bf16(aq0, bk1, zz, 0, 0, 0);
    sc[1][0] = __builtin_amdgcn_mfma_f32_16x16x32_bf16(aq1, bk0, zz, 0, 0, 0);
    sc[1][1] = __builtin_amdgcn_mfma_f32_16x16x32_bf16(aq1, bk1, zz, 0, 0, 0);

    // --- softmax over d (cols). C-layout: row=i*16+hi*4+r, col=j*16+lr ---
    const float scale = 0.17677669529663687f;
#pragma unroll
    for (int i = 0; i < 2; ++i) {
        float s0[4], s1[4], mx[4];
#pragma unroll
        for (int r = 0; r < 4; ++r) {
            s0[r] = sc[i][0][r] * scale;
            s1[r] = (lr >= 8) ? -3.0e38f : sc[i][1][r] * scale;  // mask d>=24
            mx[r] = fmaxf(s0[r], s1[r]);
        }
#pragma unroll
        for (int d = 1; d < 16; d <<= 1)
#pragma unroll
            for (int r = 0; r < 4; ++r) mx[r] = fmaxf(mx[r], __shfl_xor(mx[r], d));
        float e0[4], e1[4], sm[4];
#pragma unroll
        for (int r = 0; r < 4; ++r) {
            e0[r] = __expf(s0[r] - mx[r]);
            e1[r] = __expf(s1[r] - mx[r]);   // masked -> 0
            sm[r] = e0[r] + e1[r];
        }
#pragma unroll
        for (int d = 1; d < 16; d <<= 1)
#pragma unroll
            for (int r = 0; r < 4; ++r) sm[r] += __shfl_xor(sm[r], d);
#pragma unroll
        for (int r = 0; r < 4; ++r) {
            const float inv = 1.f / sm[r];
            const int row = i * 16 + hi * 4 + r;
            Ps[wv][row * 40 + lr]      = (bf16_t)(e0[r] * inv);
            Ps[wv][row * 40 + 16 + lr] = (bf16_t)(e1[r] * inv);
        }
    }
    // same-wave LDS write->read: program order, no barrier needed

    // --- PV: P from LDS (A-frag), V^T direct from global (B-frag) ---
    bf16x8 ap0 = *(const bf16x8*)&Ps[wv][lr * 40 + lk];
    bf16x8 ap1 = *(const bf16x8*)&Ps[wv][(16 + lr) * 40 + lk];
    bf16x8 bv0 = *(const bf16x8*)(Vt + qb + lr * 24 + lk);
    bf16x8 bv1 = *(const bf16x8*)(Vt + qb + (16 + lr) * 24 + lk);
    f32x4 o[2][2];
    o[0][0] = __builtin_amdgcn_mfma_f32_16x16x32_bf16(ap0, bv0, zz, 0, 0, 0);
    o[0][1] = __builtin_amdgcn_mfma_f32_16x16x32_bf16(ap0, bv1, zz, 0, 0, 0);
    o[1][0] = __builtin_amdgcn_mfma_f32_16x16x32_bf16(ap1, bv0, zz, 0, 0, 0);
    o[1][1] = __builtin_amdgcn_mfma_f32_16x16x32_bf16(ap1, bv1, zz, 0, 0, 0);

#pragma unroll
    for (int i = 0; i < 2; ++i)
#pragma unroll
        for (int r = 0; r < 4; ++r) {
            const int c = i * 16 + hi * 4 + r;
            if (c < 24) {
                const size_t ob = ((size_t)(b * Cn + c) * Sn + s) * En + h * Pn;
#pragma unroll
                for (int j = 0; j < 2; ++j)
                    O[ob + j * 16 + lr] = (bf16_t)o[i][j][r];
            }
        }
}

// ---------------------------------------------------------------------------
// Temporal attention, MFMA. One block (4 waves) per (b,h,c).
// ---------------------------------------------------------------------------
__global__ __launch_bounds__(256) void attn_temporal_mfma(
    const bf16_t* __restrict__ Q, const bf16_t* __restrict__ K,
    const bf16_t* __restrict__ Vt, bf16_t* __restrict__ O)
{
    const int c = blockIdx.x, h = blockIdx.y, b = blockIdx.z;
    const size_t base = ((size_t)(b * Hn + h) * Cn + c) * (Sn * Pn);

    __shared__ bf16_t Qs[128 * 32];
    __shared__ bf16_t Ks[128 * 32];
    __shared__ bf16_t Vs[32 * 136];
    __shared__ bf16_t Ps[128 * 136];

    const int tid = threadIdx.x, wv = tid >> 6, ln = tid & 63;
    const int lr = ln & 15, lk = (ln >> 4) * 8;

#pragma unroll
    for (int it = 0; it < 2; ++it) {
        const int cb = it * 256 + wv * 64;
        const int mc = cb + ln;
        const int row = mc >> 2, kc = (mc & 3) * 8;
        gl2lds16(Q + base + row * 32 + kc, &Qs[cb * 8]);
        gl2lds16(K + base + row * 32 + kc, &Ks[cb * 8]);
    }
#pragma unroll
    for (int it = 0; it < 2; ++it) {
        const int mc = it * 256 + tid;
        const int p = mc >> 4, scn = (mc & 15) * 8;
        bf16x8 v = *(const bf16x8*)(Vt + base + p * 128 + scn);
        *(bf16x8*)&Vs[p * 136 + scn] = v;
    }
    __syncthreads();

    const int r0 = wv * 32;
    bf16x8 aq0 = *(const bf16x8*)&Qs[(r0 + lr) * 32 + lk];
    bf16x8 aq1 = *(const bf16x8*)&Qs[(r0 + 16 + lr) * 32 + lk];
    f32x4 sc_[2][8];
    const f32x4 zz = {0.f, 0.f, 0.f, 0.f};
#pragma unroll
    for (int j = 0; j < 8; ++j) {
        bf16x8 bk = *(const bf16x8*)&Ks[(j * 16 + lr) * 32 + lk];
        sc_[0][j] = __builtin_amdgcn_mfma_f32_16x16x32_bf16(aq0, bk, zz, 0, 0, 0);
        sc_[1][j] = __builtin_amdgcn_mfma_f32_16x16x32_bf16(aq1, bk, zz, 0, 0, 0);
    }

    const float scale = 0.17677669529663687f;
#pragma unroll
    for (int i = 0; i < 2; ++i) {
        float mx[4], sm[4];
#pragma unroll
        for (int r = 0; r < 4; ++r) {
            float m = sc_[i][0][r];
#pragma unroll
            for (int j = 1; j < 8; ++j) m = fmaxf(m, sc_[i][j][r]);
            mx[r] = m;
        }
#pragma unroll
        for (int d = 1; d < 16; d <<= 1)
#pragma unroll
            for (int r = 0; r < 4; ++r) mx[r] = fmaxf(mx[r], __shfl_xor(mx[r], d));
#pragma unroll
        for (int r = 0; r < 4; ++r) sm[r] = 0.f;
#pragma unroll
        for (int j = 0; j < 8; ++j)
#pragma unroll
            for (int r = 0; r < 4; ++r) {
                const float e = __expf((sc_[i][j][r] - mx[r]) * scale);
                sc_[i][j][r] = e; sm[r] += e;
            }
#pragma unroll
        for (int d = 1; d < 16; d <<= 1)
#pragma unroll
            for (int r = 0; r < 4; ++r) sm[r] += __shfl_xor(sm[r], d);
        float inv[4];
#pragma unroll
        for (int r = 0; r < 4; ++r) inv[r] = 1.f / sm[r];
        const int rb = r0 + i * 16 + (ln >> 4) * 4;
#pragma unroll
        for (int j = 0; j < 8; ++j)
#pragma unroll
            for (int r = 0; r < 4; ++r)
                Ps[(rb + r) * 136 + j * 16 + lr] = (bf16_t)(sc_[i][j][r] * inv[r]);
    }
    __syncthreads();

    f32x4 o[2][2] = {};
#pragma unroll
    for (int kk = 0; kk < 4; ++kk) {
        bf16x8 ap0 = *(const bf16x8*)&Ps[(r0 + lr) * 136 + kk * 32 + lk];
        bf16x8 ap1 = *(const bf16x8*)&Ps[(r0 + 16 + lr) * 136 + kk * 32 + lk];
        bf16x8 bv0 = *(const bf16x8*)&Vs[lr * 136 + kk * 32 + lk];
        bf16x8 bv1 = *(const bf16x8*)&Vs[(16 + lr) * 136 + kk * 32 + lk];
        o[0][0] = __builtin_amdgcn_mfma_f32_16x16x32_bf16(ap0, bv0, o[0][0], 0, 0, 0);
        o[0][1] = __builtin_amdgcn_mfma_f32_16x16x32_bf16(ap0, bv1, o[0][1], 0, 0, 0);
        o[1][0] = __builtin_amdgcn_mfma_f32_16x16x32_bf16(ap1, bv0, o[1][0], 0, 0, 0);
        o[1][1] = __builtin_amdgcn_mfma_f32_16x16x32_bf16(ap1, bv1, o[1][1], 0, 0, 0);
    }

#pragma unroll
    for (int i = 0; i < 2; ++i) {
        const int sb = r0 + i * 16 + (ln >> 4) * 4;
#pragma unroll
        for (int j = 0; j < 2; ++j) {
            const int p = h * 32 + j * 16 + lr;
#pragma unroll
            for (int r = 0; r < 4; ++r)
                O[((size_t)(b * Cn + c) * Sn + (sb + r)) * En + p] = (bf16_t)o[i][j][r];
        }
    }
}

// ---------------------------------------------------------------------------
// attn_out = LN(xb + spat) + LN(xb + temp)
// ---------------------------------------------------------------------------
__global__ __launch_bounds__(256) void ln_combine_k(
    const bf16_t* __restrict__ xb, const bf16_t* __restrict__ spat,
    const bf16_t* __restrict__ temp, const float* __restrict__ g,
    const float* __restrict__ beta, bf16_t* __restrict__ AO)
{
    const int row = blockIdx.x * 4 + (threadIdx.x >> 6);
    const int lane = threadIdx.x & 63;
    const size_t off = (size_t)row * En;

    float v1[4], v2[4];
    float s1 = 0, s2 = 0, q1 = 0, q2 = 0;
#pragma unroll
    for (int i = 0; i < 4; i++) {
        const int e = lane + i * 64;
        const float xv = (float)xb[off + e];
        const float a = xv + (float)spat[off + e];
        const float t = xv + (float)temp[off + e];
        v1[i] = a; v2[i] = t;
        s1 += a; s2 += t; q1 += a * a; q2 += t * t;
    }
    for (int d = 32; d; d >>= 1) {
        s1 += __shfl_xor(s1, d); s2 += __shfl_xor(s2, d);
        q1 += __shfl_xor(q1, d); q2 += __shfl_xor(q2, d);
    }
    const float mu1 = s1 / En, mu2 = s2 / En;
    const float r1 = rsqrtf(q1 / En - mu1 * mu1 + 1e-6f);
    const float r2 = rsqrtf(q2 / En - mu2 * mu2 + 1e-6f);
#pragma unroll
    for (int i = 0; i < 4; i++) {
        const int e = lane + i * 64;
        const float out = (v1[i] - mu1) * r1 * g[e] + beta[e] +
                          (v2[i] - mu2) * r2 * g[e] + beta[e];
        AO[off + e] = (bf16_t)out;
    }
}

__global__ __launch_bounds__(256) void ln_final_k(
    const bf16_t* __restrict__ AO, const bf16_t* __restrict__ FF,
    const float* __restrict__ g, const float* __restrict__ beta,
    float* __restrict__ out)
{
    const int row = blockIdx.x * 4 + (threadIdx.x >> 6);
    const int lane = threadIdx.x & 63;
    const size_t off = (size_t)row * En;

    float v[4];
    float s = 0, q = 0;
#pragma unroll
    for (int i = 0; i < 4; i++) {
        const int e = lane + i * 64;
        const float a = (float)AO[off + e] + (float)FF[off + e];
        v[i] = a; s += a; q += a * a;
    }
    for (int d = 32; d; d >>= 1) { s += __shfl_xor(s, d); q += __shfl_xor(q, d); }
    const float mu = s / En;
    const float r = rsqrtf(q / En - mu * mu + 1e-6f);
#pragma unroll
    for (int i = 0; i < 4; i++) {
        const int e = lane + i * 64;
        out[off + e] = (v[i] - mu) * r * g[e] + beta[e];
    }
}

// ---------------------------------------------------------------------------
extern "C" void kernel_launch(void* const* d_in, const int* in_sizes, int n_in,
                              void* d_out, int out_size, void* d_ws, size_t ws_size,
                              hipStream_t stream)
{
    const float* x     = (const float*)d_in[0];
    const float* Wq_s  = (const float*)d_in[1];
    const float* Wk_s  = (const float*)d_in[2];
    const float* Wv_s  = (const float*)d_in[3];
    const float* Wo_s  = (const float*)d_in[4];
    const float* Wq_t  = (const float*)d_in[5];
    const float* Wk_t  = (const float*)d_in[6];
    const float* Wv_t  = (const float*)d_in[7];
    const float* Wo_t  = (const float*)d_in[8];
    const float* ln_g  = (const float*)d_in[9];
    const float* ln_b  = (const float*)d_in[10];
    const float* ff_w1 = (const float*)d_in[11];
    const float* ff_b1 = (const float*)d_in[12];
    const float* ff_w2 = (const float*)d_in[13];
    const float* ff_b2 = (const float*)d_in[14];
    float* out = (float*)d_out;

    bf16_t* wsb = (bf16_t*)d_ws;
    bf16_t* b0 = wsb;
    bf16_t* b1 = wsb + NBUF;
    bf16_t* b2 = wsb + 2 * NBUF;
    bf16_t* b3 = wsb + 3 * NBUF;
    bf16_t* b4 = wsb + 4 * NBUF;

    // d_out doubles as scratch: xb + 8 canonical weight slots = out bytes exactly
    bf16_t* xb = (bf16_t*)d_out;
    bf16_t* wb = xb + NBUF;
    bf16_t* w_qs = wb + 0 * WSLOT;
    bf16_t* w_os = wb + 1 * WSLOT;
    bf16_t* w_qt = wb + 2 * WSLOT;
    bf16_t* w_kt = wb + 3 * WSLOT;
    bf16_t* w_vt = wb + 4 * WSLOT;
    bf16_t* w_ot = wb + 5 * WSLOT;
    bf16_t* w_f1 = wb + 6 * WSLOT;
    bf16_t* w_f2 = wb + 7 * WSLOT;
    bf16_t* w_ks = b4 + NBUF - 2 * 65536;   // b4 first written after these die
    bf16_t* w_vs = b4 + NBUF - 65536;

    // strides
    const int XAb = Cn * Sn * En, XAc = Sn * En, XAs = En;                        // [B,C,S,E]
    const int QSb = Sn * Hn * Cn * Pn, QSs = Hn * Cn * Pn, QSh = Cn * Pn;         // [B,S,H,C,P]
    const int VTb = Sn * Hn * Pn * Cn, VTs = Hn * Pn * Cn, VTh = Pn * Cn;         // [B,S,H,P,C]
    const int QTb = Hn * Cn * Sn * Pn, QTh = Cn * Sn * Pn, QTc = Sn * Pn, QTs = Pn; // [B,H,C,S,P]
    const int WCP = 256 * 256;

    // --- conversions (2 big + 2 small launches) ---
    conv_x_k<<<NBUF / 1024, 256, 0, stream>>>(x, xb);
    conv_w8_k<<<dim3(6144, 8), 256, 0, stream>>>(
        CDesc{Wq_s, Pn * En, Cn * Pn * En, En, 1},        // slot0 w_qs
        CDesc{Wo_s, En * En, 32, 1, En},                  // slot1 w_os
        CDesc{Wq_t, En * Pn, Cn * En * Pn, 1, Pn},        // slot2 w_qt
        CDesc{Wk_t, En * Pn, Cn * En * Pn, 1, Pn},        // slot3 w_kt
        CDesc{Wv_t, En * Pn, Cn * En * Pn, 1, Pn},        // slot4 w_vt
        CDesc{Wo_t, En * En, 32, 1, En},                  // slot5 w_ot
        CDesc{ff_w1, En * En, 32, 1, En},                 // slot6 w_f1
        CDesc{ff_w2, En * En, 32, 1, En},                 // slot7 w_f2
        wb);
    conv_w_k<<<256, 256, 0, stream>>>(Wk_s, w_ks, 0, En * Pn, 1, Pn);
    conv_w_k<<<256, 256, 0, stream>>>(Wv_s, w_vs, 0, En * Pn, 1, Pn);

    // --- spatial branch: fused QKV (V written pre-transposed [b,s,h,p,c]) ---
    gemm_mfma<3, 0><<<dim3(16, 6, 24), 256, 0, stream>>>(
        xb, XAb, XAc, XAs,
        GDesc{w_qs, b0, WCP, QSb, Pn, QSs, QSh, 1},
        GDesc{w_ks, b1, 0,   QSb, Pn, QSs, QSh, 1},
        GDesc{w_vs, b2, 0,   VTb, 1,  VTs, VTh, Cn},
        nullptr);
    attn_spatial_mfma<<<Bn * Sn * Hn / 4, 256, 0, stream>>>(b0, b1, b2, b3);
    gemm_mfma<1, 0><<<dim3(16, 2, 24), 256, 0, stream>>>(
        b3, XAb, XAc, XAs,
        GDesc{w_os, b4, WCP, XAb, XAc, XAs, 32, 1},
        GDesc{w_os, b4, WCP, XAb, XAc, XAs, 32, 1},
        GDesc{w_os, b4, WCP, XAb, XAc, XAs, 32, 1}, nullptr);

    // --- temporal branch: fused QKV (V pre-transposed [b,h,c,p,s]) ---
    gemm_mfma<3, 0><<<dim3(16, 6, 24), 256, 0, stream>>>(
        xb, XAb, XAc, XAs,
        GDesc{w_qt, b0, WCP, QTb, QTc, QTs, QTh, 1},
        GDesc{w_kt, b1, WCP, QTb, QTc, QTs, QTh, 1},
        GDesc{w_vt, b2, WCP, QTb, QTc, 1, QTh, Sn},
        nullptr);
    attn_temporal_mfma<<<dim3(24, 8, 16), 256, 0, stream>>>(b0, b1, b2, b3);
    gemm_mfma<1, 0><<<dim3(16, 2, 24), 256, 0, stream>>>(
        b3, XAb, XAc, XAs,
        GDesc{w_ot, b0, WCP, XAb, XAc, XAs, 32, 1},
        GDesc{w_ot, b0, WCP, XAb, XAc, XAs, 32, 1},
        GDesc{w_ot, b0, WCP, XAb, XAc, XAs, 32, 1}, nullptr);

    // --- combine + FF + final LN ---
    ln_combine_k<<<NROWS / 4, 256, 0, stream>>>(xb, b4, b0, ln_g, ln_b, b1);
    gemm_mfma<1, 1><<<dim3(16, 2, 24), 256, 0, stream>>>(
        b1, XAb, XAc, XAs,
        GDesc{w_f1, b2, WCP, XAb, XAc, XAs, 32, 1},
        GDesc{w_f1, b2, WCP, XAb, XAc, XAs, 32, 1},
        GDesc{w_f1, b2, WCP, XAb, XAc, XAs, 32, 1}, ff_b1);
    gemm_mfma<1, 2><<<dim3(16, 2, 24), 256, 0, stream>>>(
        b2, XAb, XAc, XAs,
        GDesc{w_f2, b3, WCP, XAb, XAc, XAs, 32, 1},
        GDesc{w_f2, b3, WCP, XAb, XAc, XAs, 32, 1},
        GDesc{w_f2, b3, WCP, XAb, XAc, XAs, 32, 1}, ff_b2);
    ln_final_k<<<NROWS / 4, 256, 0, stream>>>(b1, b3, ln_g, ln_b, out);
}

// Round 4
// 450.272 us; speedup vs baseline: 3.9295x; 1.1755x over previous
//
#include <hip/hip_runtime.h>
#include <hip/hip_bf16.h>

constexpr int Bn = 16, Cn = 24, Sn = 128, En = 256, Hn = 8, Pn = 32;
constexpr int NROWS = Bn * Cn * Sn;                  // 49152
constexpr size_t NBUF = (size_t)Bn * Cn * Sn * En;   // 12,582,912 elems
constexpr size_t WSLOT = (size_t)Cn * 256 * 256;     // 1,572,864

typedef __bf16 bf16_t;
typedef bf16_t bf16x8 __attribute__((ext_vector_type(8)));
typedef bf16_t bf16x4 __attribute__((ext_vector_type(4)));
typedef float f32x4 __attribute__((ext_vector_type(4)));

// global -> LDS direct 16B copy (dest = wave-uniform base + lane*16)
__device__ __forceinline__ void gl2lds16(const bf16_t* g, bf16_t* l) {
    typedef const __attribute__((address_space(1))) unsigned int* gp_t;
    typedef __attribute__((address_space(3))) unsigned int* lp_t;
    __builtin_amdgcn_global_load_lds((gp_t)(unsigned long long)g,
                                     (lp_t)(unsigned int)(unsigned long long)l,
                                     16, 0, 0);
}

// ---------------------------------------------------------------------------
// x fp32 -> bf16
// ---------------------------------------------------------------------------
__global__ __launch_bounds__(256) void conv_x_k(const float* __restrict__ x,
                                                bf16_t* __restrict__ xb) {
    const size_t i = ((size_t)blockIdx.x * 256 + threadIdx.x) * 4;
    const float4 v = *(const float4*)(x + i);
    bf16x4 o = {(bf16_t)v.x, (bf16_t)v.y, (bf16_t)v.z, (bf16_t)v.w};
    *(bf16x4*)(xb + i) = o;
}

// ---------------------------------------------------------------------------
// fused weight gather -> canonical bf16 [slot][c][n][e]; blockIdx.y = slot
// ---------------------------------------------------------------------------
struct CDesc { const float* W; int Sc, Snh, Snp, Se; };

__global__ __launch_bounds__(256) void conv_w8_k(
    CDesc d0, CDesc d1, CDesc d2, CDesc d3, CDesc d4, CDesc d5, CDesc d6, CDesc d7,
    bf16_t* __restrict__ out)
{
    CDesc d;
    switch (blockIdx.y) {
        case 0: d = d0; break; case 1: d = d1; break;
        case 2: d = d2; break; case 3: d = d3; break;
        case 4: d = d4; break; case 5: d = d5; break;
        case 6: d = d6; break; default: d = d7; break;
    }
    const int n = blockIdx.x & 255, c = blockIdx.x >> 8;
    const int e = threadIdx.x;
    out[(size_t)blockIdx.y * WSLOT + (size_t)blockIdx.x * 256 + e] =
        (bf16_t)d.W[(size_t)c * d.Sc + (size_t)(n >> 5) * d.Snh + (n & 31) * d.Snp +
                    (size_t)e * d.Se];
}

__global__ __launch_bounds__(256) void conv_w_k(const float* __restrict__ W,
                                                bf16_t* __restrict__ Wb,
                                                int Sc, int Snh, int Snp, int Se) {
    const int n = blockIdx.x & 255, c = blockIdx.x >> 8;
    const int e = threadIdx.x;
    Wb[(size_t)blockIdx.x * 256 + e] =
        (bf16_t)W[(size_t)c * Sc + (size_t)(n >> 5) * Snh + (n & 31) * Snp + (size_t)e * Se];
}

// ---------------------------------------------------------------------------
// bf16 MFMA GEMM, up to 3 fused projections sharing A, LDS-staged epilogue.
// trans=0: output n-inner (Onp==1, 32-groups via Onh); stage [m][136].
// trans=1: output m-inner (Os==1); stage [n][136], 16B stores along m.
// EPI: 0 / 1 (bias+relu) / 2 (bias)  (trans=0 path only)
// ---------------------------------------------------------------------------
struct GDesc { const bf16_t* W; bf16_t* O; int Wc, Ob, Oc, Os, Onh, Onp, trans; };

template <int NP, int EPI>
__global__ __launch_bounds__(256) void gemm_mfma(
    const bf16_t* __restrict__ A, int Ab, int Ac, int As,
    GDesc g0, GDesc g1, GDesc g2, const float* __restrict__ bias)
{
    const int b = blockIdx.x, c = blockIdx.z;
    const int proj = (NP == 1) ? 0 : ((int)blockIdx.y >> 1);
    const int nt = (NP == 1) ? (int)blockIdx.y : ((int)blockIdx.y & 1);
    GDesc g = (proj == 0) ? g0 : (proj == 1) ? g1 : g2;

    __shared__ bf16_t As_lds[128 * 32];
    __shared__ bf16_t Bs_lds[128 * 32];
    __shared__ bf16_t Cs[64 * 136];      // epilogue staging (17408 B)

    const int tid = threadIdx.x, wv = tid >> 6, ln = tid & 63;
    const int wm = (wv >> 1) * 64, wn = (wv & 1) * 64;
    const int lr = ln & 15, hi = ln >> 4, lk = hi * 8;

    const bf16_t* Abase = A + (size_t)b * Ab + (size_t)c * Ac;
    const bf16_t* Bbase = g.W + (size_t)c * g.Wc + (size_t)(nt * 128) * 256;

    f32x4 acc[4][4] = {};

    for (int k0 = 0; k0 < 256; k0 += 32) {
#pragma unroll
        for (int it = 0; it < 2; ++it) {
            const int cb = it * 256 + wv * 64;
            const int mc = cb + ln;
            const int row = mc >> 2, kc = (mc & 3) * 8;
            gl2lds16(Abase + (size_t)row * As + k0 + kc, &As_lds[cb * 8]);
            gl2lds16(Bbase + (size_t)row * 256 + k0 + kc, &Bs_lds[cb * 8]);
        }
        __syncthreads();

        bf16x8 af[4], bfr[4];
#pragma unroll
        for (int i = 0; i < 4; ++i)
            af[i] = *(const bf16x8*)&As_lds[(wm + i * 16 + lr) * 32 + lk];
#pragma unroll
        for (int j = 0; j < 4; ++j)
            bfr[j] = *(const bf16x8*)&Bs_lds[(wn + j * 16 + lr) * 32 + lk];
#pragma unroll
        for (int i = 0; i < 4; ++i)
#pragma unroll
            for (int j = 0; j < 4; ++j)
                acc[i][j] = __builtin_amdgcn_mfma_f32_16x16x32_bf16(af[i], bfr[j], acc[i][j], 0, 0, 0);
        __syncthreads();
    }

    // ---- LDS-staged epilogue: two 64-row (or 64-col) passes ----
#pragma unroll
    for (int pass = 0; pass < 2; ++pass) {
        if (!g.trans) {
            // stage rows [64*pass, 64*pass+64) as Cs[m_local][n], pitch 136
            if (wm == pass * 64) {
#pragma unroll
                for (int i = 0; i < 4; ++i)
#pragma unroll
                    for (int j = 0; j < 4; ++j) {
                        const int n = nt * 128 + wn + j * 16 + lr;
                        float bv = 0.f;
                        if (EPI) bv = bias[c * 256 + n];
#pragma unroll
                        for (int r = 0; r < 4; ++r) {
                            float v = acc[i][j][r];
                            if (EPI) { v += bv; if (EPI == 1) v = fmaxf(v, 0.f); }
                            Cs[(i * 16 + hi * 4 + r) * 136 + wn + j * 16 + lr] = (bf16_t)v;
                        }
                    }
            }
            __syncthreads();
#pragma unroll
            for (int it = 0; it < 2; ++it) {
                const int lrow = it * 32 + (tid >> 3);
                const int n0 = (tid & 7) * 16;
                bf16x8 v0 = *(const bf16x8*)&Cs[lrow * 136 + n0];
                bf16x8 v1 = *(const bf16x8*)&Cs[lrow * 136 + n0 + 8];
                const int m = pass * 64 + lrow;
                const int n = nt * 128 + n0;
                bf16_t* dst = g.O + (size_t)b * g.Ob + (size_t)c * g.Oc +
                              (size_t)m * g.Os + (size_t)(n >> 5) * g.Onh + (n & 31);
                *(bf16x8*)dst = v0;
                *(bf16x8*)(dst + 8) = v1;   // n0..n0+15 stays inside one 32-group
            }
            __syncthreads();
        } else {
            // stage cols [64*pass, 64*pass+64) as Cs[n_local][m], pitch 136
            if (wn == pass * 64) {
#pragma unroll
                for (int i = 0; i < 4; ++i)
#pragma unroll
                    for (int j = 0; j < 4; ++j) {
                        bf16x4 pk = {(bf16_t)acc[i][j][0], (bf16_t)acc[i][j][1],
                                     (bf16_t)acc[i][j][2], (bf16_t)acc[i][j][3]};
                        *(bf16x4*)&Cs[(j * 16 + lr) * 136 + wm + i * 16 + hi * 4] = pk;
                    }
            }
            __syncthreads();
#pragma unroll
            for (int it = 0; it < 2; ++it) {
                const int lrow = it * 32 + (tid >> 3);          // local n
                const int m0 = (tid & 7) * 16;
                bf16x8 v0 = *(const bf16x8*)&Cs[lrow * 136 + m0];
                bf16x8 v1 = *(const bf16x8*)&Cs[lrow * 136 + m0 + 8];
                const int n = nt * 128 + pass * 64 + lrow;
                bf16_t* dst = g.O + (size_t)b * g.Ob + (size_t)c * g.Oc +
                              (size_t)(n >> 5) * g.Onh + (size_t)(n & 31) * g.Onp + m0;
                *(bf16x8*)dst = v0;
                *(bf16x8*)(dst + 8) = v1;   // m-contiguous (Os==1)
            }
            __syncthreads();
        }
    }
}

// ---------------------------------------------------------------------------
// Spatial attention, MFMA, one wave per (b,s,h). 24x24 padded to 32.
// Q,K,V: [b,s,h,c,p] (k=p contiguous). Q/K frags load directly from global;
// V transposed to [p][d] in per-wave LDS (pad d>=24 zeroed: P cols there are
// exact zeros but 0*NaN would poison, so the pad must be finite).
// ---------------------------------------------------------------------------
__global__ __launch_bounds__(256) void attn_spatial_mfma(
    const bf16_t* __restrict__ Q, const bf16_t* __restrict__ K,
    const bf16_t* __restrict__ V, bf16_t* __restrict__ O)
{
    __shared__ bf16_t Ps[4][32 * 40];   // per-wave P, pitch 40
    __shared__ bf16_t Vt[4][32 * 40];   // per-wave V^T [p][d], pitch 40

    const int tid = threadIdx.x, wv = tid >> 6, ln = tid & 63;
    const int lr = ln & 15, hi = ln >> 4, lk = hi * 8;

    const int bsh = blockIdx.x * 4 + wv;
    const int h = bsh & 7, s = (bsh >> 3) & 127, b = bsh >> 10;
    const size_t qb = (size_t)bsh * (Cn * Pn);   // 768 elems per unit

    // zero the d in [24,32) pad of Vt
    {
        const int p = ln >> 1, c0 = 24 + (ln & 1) * 4;
        bf16x4 z = {};
        *(bf16x4*)&Vt[wv][p * 40 + c0] = z;
    }
    // load V rows coalesced, scatter transposed into Vt
#pragma unroll
    for (int it = 0; it < 2; ++it) {
        const int ch = it * 64 + ln;
        if (ch < 96) {
            const int cc = ch >> 2, p0 = (ch & 3) * 8;
            bf16x8 v = *(const bf16x8*)(V + qb + cc * 32 + p0);
#pragma unroll
            for (int j = 0; j < 8; ++j)
                Vt[wv][(p0 + j) * 40 + cc] = v[j];
        }
    }

    // --- QK^T: direct global frag loads ---
    bf16x8 aq0 = *(const bf16x8*)(Q + qb + lr * 32 + lk);
    bf16x8 aq1 = *(const bf16x8*)(Q + qb + (16 + lr) * 32 + lk);
    bf16x8 bk0 = *(const bf16x8*)(K + qb + lr * 32 + lk);
    bf16x8 bk1 = *(const bf16x8*)(K + qb + (16 + lr) * 32 + lk);
    const f32x4 zz = {0.f, 0.f, 0.f, 0.f};
    f32x4 sc[2][2];
    sc[0][0] = __builtin_amdgcn_mfma_f32_16x16x32_bf16(aq0, bk0, zz, 0, 0, 0);
    sc[0][1] = __builtin_amdgcn_mfma_f32_16x16x32_bf16(aq0, bk1, zz, 0, 0, 0);
    sc[1][0] = __builtin_amdgcn_mfma_f32_16x16x32_bf16(aq1, bk0, zz, 0, 0, 0);
    sc[1][1] = __builtin_amdgcn_mfma_f32_16x16x32_bf16(aq1, bk1, zz, 0, 0, 0);

    // --- softmax over d (cols); row=i*16+hi*4+r, col=j*16+lr ---
    const float scale = 0.17677669529663687f;
#pragma unroll
    for (int i = 0; i < 2; ++i) {
        float s0[4], s1[4], mx[4];
#pragma unroll
        for (int r = 0; r < 4; ++r) {
            s0[r] = sc[i][0][r] * scale;
            s1[r] = (lr >= 8) ? -3.0e38f : sc[i][1][r] * scale;  // mask d>=24
            mx[r] = fmaxf(s0[r], s1[r]);
        }
#pragma unroll
        for (int d = 1; d < 16; d <<= 1)
#pragma unroll
            for (int r = 0; r < 4; ++r) mx[r] = fmaxf(mx[r], __shfl_xor(mx[r], d));
        float e0[4], e1[4], sm[4];
#pragma unroll
        for (int r = 0; r < 4; ++r) {
            e0[r] = __expf(s0[r] - mx[r]);
            e1[r] = __expf(s1[r] - mx[r]);   // masked -> 0
            sm[r] = e0[r] + e1[r];
        }
#pragma unroll
        for (int d = 1; d < 16; d <<= 1)
#pragma unroll
            for (int r = 0; r < 4; ++r) sm[r] += __shfl_xor(sm[r], d);
#pragma unroll
        for (int r = 0; r < 4; ++r) {
            const float inv = 1.f / sm[r];
            const int row = i * 16 + hi * 4 + r;
            Ps[wv][row * 40 + lr]      = (bf16_t)(e0[r] * inv);
            Ps[wv][row * 40 + 16 + lr] = (bf16_t)(e1[r] * inv);
        }
    }
    // same-wave LDS write->read: program order, no barrier needed

    // --- PV ---
    bf16x8 ap0 = *(const bf16x8*)&Ps[wv][lr * 40 + lk];
    bf16x8 ap1 = *(const bf16x8*)&Ps[wv][(16 + lr) * 40 + lk];
    bf16x8 bv0 = *(const bf16x8*)&Vt[wv][lr * 40 + lk];
    bf16x8 bv1 = *(const bf16x8*)&Vt[wv][(16 + lr) * 40 + lk];
    f32x4 o[2][2];
    o[0][0] = __builtin_amdgcn_mfma_f32_16x16x32_bf16(ap0, bv0, zz, 0, 0, 0);
    o[0][1] = __builtin_amdgcn_mfma_f32_16x16x32_bf16(ap0, bv1, zz, 0, 0, 0);
    o[1][0] = __builtin_amdgcn_mfma_f32_16x16x32_bf16(ap1, bv0, zz, 0, 0, 0);
    o[1][1] = __builtin_amdgcn_mfma_f32_16x16x32_bf16(ap1, bv1, zz, 0, 0, 0);

#pragma unroll
    for (int i = 0; i < 2; ++i)
#pragma unroll
        for (int r = 0; r < 4; ++r) {
            const int c = i * 16 + hi * 4 + r;
            if (c < 24) {
                const size_t ob = ((size_t)(b * Cn + c) * Sn + s) * En + h * Pn;
#pragma unroll
                for (int j = 0; j < 2; ++j)
                    O[ob + j * 16 + lr] = (bf16_t)o[i][j][r];
            }
        }
}

// ---------------------------------------------------------------------------
// Temporal attention, MFMA. One block (4 waves) per (b,h,c).
// ---------------------------------------------------------------------------
__global__ __launch_bounds__(256) void attn_temporal_mfma(
    const bf16_t* __restrict__ Q, const bf16_t* __restrict__ K,
    const bf16_t* __restrict__ Vt, bf16_t* __restrict__ O)
{
    const int c = blockIdx.x, h = blockIdx.y, b = blockIdx.z;
    const size_t base = ((size_t)(b * Hn + h) * Cn + c) * (Sn * Pn);

    __shared__ bf16_t Qs[128 * 32];
    __shared__ bf16_t Ks[128 * 32];
    __shared__ bf16_t Vs[32 * 136];
    __shared__ bf16_t Ps[128 * 136];

    const int tid = threadIdx.x, wv = tid >> 6, ln = tid & 63;
    const int lr = ln & 15, lk = (ln >> 4) * 8;

#pragma unroll
    for (int it = 0; it < 2; ++it) {
        const int cb = it * 256 + wv * 64;
        const int mc = cb + ln;
        const int row = mc >> 2, kc = (mc & 3) * 8;
        gl2lds16(Q + base + row * 32 + kc, &Qs[cb * 8]);
        gl2lds16(K + base + row * 32 + kc, &Ks[cb * 8]);
    }
#pragma unroll
    for (int it = 0; it < 2; ++it) {
        const int mc = it * 256 + tid;
        const int p = mc >> 4, scn = (mc & 15) * 8;
        bf16x8 v = *(const bf16x8*)(Vt + base + p * 128 + scn);
        *(bf16x8*)&Vs[p * 136 + scn] = v;
    }
    __syncthreads();

    const int r0 = wv * 32;
    bf16x8 aq0 = *(const bf16x8*)&Qs[(r0 + lr) * 32 + lk];
    bf16x8 aq1 = *(const bf16x8*)&Qs[(r0 + 16 + lr) * 32 + lk];
    f32x4 sc_[2][8];
    const f32x4 zz = {0.f, 0.f, 0.f, 0.f};
#pragma unroll
    for (int j = 0; j < 8; ++j) {
        bf16x8 bk = *(const bf16x8*)&Ks[(j * 16 + lr) * 32 + lk];
        sc_[0][j] = __builtin_amdgcn_mfma_f32_16x16x32_bf16(aq0, bk, zz, 0, 0, 0);
        sc_[1][j] = __builtin_amdgcn_mfma_f32_16x16x32_bf16(aq1, bk, zz, 0, 0, 0);
    }

    const float scale = 0.17677669529663687f;
#pragma unroll
    for (int i = 0; i < 2; ++i) {
        float mx[4], sm[4];
#pragma unroll
        for (int r = 0; r < 4; ++r) {
            float m = sc_[i][0][r];
#pragma unroll
            for (int j = 1; j < 8; ++j) m = fmaxf(m, sc_[i][j][r]);
            mx[r] = m;
        }
#pragma unroll
        for (int d = 1; d < 16; d <<= 1)
#pragma unroll
            for (int r = 0; r < 4; ++r) mx[r] = fmaxf(mx[r], __shfl_xor(mx[r], d));
#pragma unroll
        for (int r = 0; r < 4; ++r) sm[r] = 0.f;
#pragma unroll
        for (int j = 0; j < 8; ++j)
#pragma unroll
            for (int r = 0; r < 4; ++r) {
                const float e = __expf((sc_[i][j][r] - mx[r]) * scale);
                sc_[i][j][r] = e; sm[r] += e;
            }
#pragma unroll
        for (int d = 1; d < 16; d <<= 1)
#pragma unroll
            for (int r = 0; r < 4; ++r) sm[r] += __shfl_xor(sm[r], d);
        float inv[4];
#pragma unroll
        for (int r = 0; r < 4; ++r) inv[r] = 1.f / sm[r];
        const int rb = r0 + i * 16 + (ln >> 4) * 4;
#pragma unroll
        for (int j = 0; j < 8; ++j)
#pragma unroll
            for (int r = 0; r < 4; ++r)
                Ps[(rb + r) * 136 + j * 16 + lr] = (bf16_t)(sc_[i][j][r] * inv[r]);
    }
    __syncthreads();

    f32x4 o[2][2] = {};
#pragma unroll
    for (int kk = 0; kk < 4; ++kk) {
        bf16x8 ap0 = *(const bf16x8*)&Ps[(r0 + lr) * 136 + kk * 32 + lk];
        bf16x8 ap1 = *(const bf16x8*)&Ps[(r0 + 16 + lr) * 136 + kk * 32 + lk];
        bf16x8 bv0 = *(const bf16x8*)&Vs[lr * 136 + kk * 32 + lk];
        bf16x8 bv1 = *(const bf16x8*)&Vs[(16 + lr) * 136 + kk * 32 + lk];
        o[0][0] = __builtin_amdgcn_mfma_f32_16x16x32_bf16(ap0, bv0, o[0][0], 0, 0, 0);
        o[0][1] = __builtin_amdgcn_mfma_f32_16x16x32_bf16(ap0, bv1, o[0][1], 0, 0, 0);
        o[1][0] = __builtin_amdgcn_mfma_f32_16x16x32_bf16(ap1, bv0, o[1][0], 0, 0, 0);
        o[1][1] = __builtin_amdgcn_mfma_f32_16x16x32_bf16(ap1, bv1, o[1][1], 0, 0, 0);
    }

#pragma unroll
    for (int i = 0; i < 2; ++i) {
        const int sb = r0 + i * 16 + (ln >> 4) * 4;
#pragma unroll
        for (int j = 0; j < 2; ++j) {
            const int p = h * 32 + j * 16 + lr;
#pragma unroll
            for (int r = 0; r < 4; ++r)
                O[((size_t)(b * Cn + c) * Sn + (sb + r)) * En + p] = (bf16_t)o[i][j][r];
        }
    }
}

// ---------------------------------------------------------------------------
// attn_out = LN(xb + spat) + LN(xb + temp)
// ---------------------------------------------------------------------------
__global__ __launch_bounds__(256) void ln_combine_k(
    const bf16_t* __restrict__ xb, const bf16_t* __restrict__ spat,
    const bf16_t* __restrict__ temp, const float* __restrict__ g,
    const float* __restrict__ beta, bf16_t* __restrict__ AO)
{
    const int row = blockIdx.x * 4 + (threadIdx.x >> 6);
    const int lane = threadIdx.x & 63;
    const size_t off = (size_t)row * En;

    float v1[4], v2[4];
    float s1 = 0, s2 = 0, q1 = 0, q2 = 0;
#pragma unroll
    for (int i = 0; i < 4; i++) {
        const int e = lane + i * 64;
        const float xv = (float)xb[off + e];
        const float a = xv + (float)spat[off + e];
        const float t = xv + (float)temp[off + e];
        v1[i] = a; v2[i] = t;
        s1 += a; s2 += t; q1 += a * a; q2 += t * t;
    }
    for (int d = 32; d; d >>= 1) {
        s1 += __shfl_xor(s1, d); s2 += __shfl_xor(s2, d);
        q1 += __shfl_xor(q1, d); q2 += __shfl_xor(q2, d);
    }
    const float mu1 = s1 / En, mu2 = s2 / En;
    const float r1 = rsqrtf(q1 / En - mu1 * mu1 + 1e-6f);
    const float r2 = rsqrtf(q2 / En - mu2 * mu2 + 1e-6f);
#pragma unroll
    for (int i = 0; i < 4; i++) {
        const int e = lane + i * 64;
        const float out = (v1[i] - mu1) * r1 * g[e] + beta[e] +
                          (v2[i] - mu2) * r2 * g[e] + beta[e];
        AO[off + e] = (bf16_t)out;
    }
}

__global__ __launch_bounds__(256) void ln_final_k(
    const bf16_t* __restrict__ AO, const bf16_t* __restrict__ FF,
    const float* __restrict__ g, const float* __restrict__ beta,
    float* __restrict__ out)
{
    const int row = blockIdx.x * 4 + (threadIdx.x >> 6);
    const int lane = threadIdx.x & 63;
    const size_t off = (size_t)row * En;

    float v[4];
    float s = 0, q = 0;
#pragma unroll
    for (int i = 0; i < 4; i++) {
        const int e = lane + i * 64;
        const float a = (float)AO[off + e] + (float)FF[off + e];
        v[i] = a; s += a; q += a * a;
    }
    for (int d = 32; d; d >>= 1) { s += __shfl_xor(s, d); q += __shfl_xor(q, d); }
    const float mu = s / En;
    const float r = rsqrtf(q / En - mu * mu + 1e-6f);
#pragma unroll
    for (int i = 0; i < 4; i++) {
        const int e = lane + i * 64;
        out[off + e] = (v[i] - mu) * r * g[e] + beta[e];
    }
}

// ---------------------------------------------------------------------------
extern "C" void kernel_launch(void* const* d_in, const int* in_sizes, int n_in,
                              void* d_out, int out_size, void* d_ws, size_t ws_size,
                              hipStream_t stream)
{
    const float* x     = (const float*)d_in[0];
    const float* Wq_s  = (const float*)d_in[1];
    const float* Wk_s  = (const float*)d_in[2];
    const float* Wv_s  = (const float*)d_in[3];
    const float* Wo_s  = (const float*)d_in[4];
    const float* Wq_t  = (const float*)d_in[5];
    const float* Wk_t  = (const float*)d_in[6];
    const float* Wv_t  = (const float*)d_in[7];
    const float* Wo_t  = (const float*)d_in[8];
    const float* ln_g  = (const float*)d_in[9];
    const float* ln_b  = (const float*)d_in[10];
    const float* ff_w1 = (const float*)d_in[11];
    const float* ff_b1 = (const float*)d_in[12];
    const float* ff_w2 = (const float*)d_in[13];
    const float* ff_b2 = (const float*)d_in[14];
    float* out = (float*)d_out;

    bf16_t* wsb = (bf16_t*)d_ws;
    bf16_t* b0 = wsb;
    bf16_t* b1 = wsb + NBUF;
    bf16_t* b2 = wsb + 2 * NBUF;
    bf16_t* b3 = wsb + 3 * NBUF;
    bf16_t* b4 = wsb + 4 * NBUF;

    // d_out doubles as scratch: xb + 8 canonical weight slots
    bf16_t* xb = (bf16_t*)d_out;
    bf16_t* wb = xb + NBUF;
    bf16_t* w_qs = wb + 0 * WSLOT;
    bf16_t* w_os = wb + 1 * WSLOT;
    bf16_t* w_qt = wb + 2 * WSLOT;
    bf16_t* w_kt = wb + 3 * WSLOT;
    bf16_t* w_vt = wb + 4 * WSLOT;
    bf16_t* w_ot = wb + 5 * WSLOT;
    bf16_t* w_f1 = wb + 6 * WSLOT;
    bf16_t* w_f2 = wb + 7 * WSLOT;
    bf16_t* w_ks = b4 + NBUF - 2 * 65536;   // b4 first written after these die
    bf16_t* w_vs = b4 + NBUF - 65536;

    // strides
    const int XAb = Cn * Sn * En, XAc = Sn * En, XAs = En;                          // [B,C,S,E]
    const int QSb = Sn * Hn * Cn * Pn, QSs = Hn * Cn * Pn, QSh = Cn * Pn;           // [B,S,H,C,P]
    const int QTb = Hn * Cn * Sn * Pn, QTh = Cn * Sn * Pn, QTc = Sn * Pn, QTs = Pn; // [B,H,C,S,P]
    const int WCP = 256 * 256;

    // --- conversions ---
    conv_x_k<<<NBUF / 1024, 256, 0, stream>>>(x, xb);
    conv_w8_k<<<dim3(6144, 8), 256, 0, stream>>>(
        CDesc{Wq_s, Pn * En, Cn * Pn * En, En, 1},
        CDesc{Wo_s, En * En, 32, 1, En},
        CDesc{Wq_t, En * Pn, Cn * En * Pn, 1, Pn},
        CDesc{Wk_t, En * Pn, Cn * En * Pn, 1, Pn},
        CDesc{Wv_t, En * Pn, Cn * En * Pn, 1, Pn},
        CDesc{Wo_t, En * En, 32, 1, En},
        CDesc{ff_w1, En * En, 32, 1, En},
        CDesc{ff_w2, En * En, 32, 1, En},
        wb);
    conv_w_k<<<256, 256, 0, stream>>>(Wk_s, w_ks, 0, En * Pn, 1, Pn);
    conv_w_k<<<256, 256, 0, stream>>>(Wv_s, w_vs, 0, En * Pn, 1, Pn);

    // --- spatial branch: fused QKV, all [B,S,H,C,P] (V transposed in-kernel) ---
    gemm_mfma<3, 0><<<dim3(16, 6, 24), 256, 0, stream>>>(
        xb, XAb, XAc, XAs,
        GDesc{w_qs, b0, WCP, QSb, Pn, QSs, QSh, 1, 0},
        GDesc{w_ks, b1, 0,   QSb, Pn, QSs, QSh, 1, 0},
        GDesc{w_vs, b2, 0,   QSb, Pn, QSs, QSh, 1, 0},
        nullptr);
    attn_spatial_mfma<<<Bn * Sn * Hn / 4, 256, 0, stream>>>(b0, b1, b2, b3);
    gemm_mfma<1, 0><<<dim3(16, 2, 24), 256, 0, stream>>>(
        b3, XAb, XAc, XAs,
        GDesc{w_os, b4, WCP, XAb, XAc, XAs, 32, 1, 0},
        GDesc{w_os, b4, WCP, XAb, XAc, XAs, 32, 1, 0},
        GDesc{w_os, b4, WCP, XAb, XAc, XAs, 32, 1, 0}, nullptr);

    // --- temporal branch: fused QKV (V pre-transposed [b,h,c,p,s] via trans=1) ---
    gemm_mfma<3, 0><<<dim3(16, 6, 24), 256, 0, stream>>>(
        xb, XAb, XAc, XAs,
        GDesc{w_qt, b0, WCP, QTb, QTc, QTs, QTh, 1, 0},
        GDesc{w_kt, b1, WCP, QTb, QTc, QTs, QTh, 1, 0},
        GDesc{w_vt, b2, WCP, QTb, QTc, 1, QTh, Sn, 1},
        nullptr);
    attn_temporal_mfma<<<dim3(24, 8, 16), 256, 0, stream>>>(b0, b1, b2, b3);
    gemm_mfma<1, 0><<<dim3(16, 2, 24), 256, 0, stream>>>(
        b3, XAb, XAc, XAs,
        GDesc{w_ot, b0, WCP, XAb, XAc, XAs, 32, 1, 0},
        GDesc{w_ot, b0, WCP, XAb, XAc, XAs, 32, 1, 0},
        GDesc{w_ot, b0, WCP, XAb, XAc, XAs, 32, 1, 0}, nullptr);

    // --- combine + FF + final LN ---
    ln_combine_k<<<NROWS / 4, 256, 0, stream>>>(xb, b4, b0, ln_g, ln_b, b1);
    gemm_mfma<1, 1><<<dim3(16, 2, 24), 256, 0, stream>>>(
        b1, XAb, XAc, XAs,
        GDesc{w_f1, b2, WCP, XAb, XAc, XAs, 32, 1, 0},
        GDesc{w_f1, b2, WCP, XAb, XAc, XAs, 32, 1, 0},
        GDesc{w_f1, b2, WCP, XAb, XAc, XAs, 32, 1, 0}, ff_b1);
    gemm_mfma<1, 2><<<dim3(16, 2, 24), 256, 0, stream>>>(
        b2, XAb, XAc, XAs,
        GDesc{w_f2, b3, WCP, XAb, XAc, XAs, 32, 1, 0},
        GDesc{w_f2, b3, WCP, XAb, XAc, XAs, 32, 1, 0},
        GDesc{w_f2, b3, WCP, XAb, XAc, XAs, 32, 1, 0}, ff_b2);
    ln_final_k<<<NROWS / 4, 256, 0, stream>>>(b1, b3, ln_g, ln_b, out);
}

// Round 5
// 407.784 us; speedup vs baseline: 4.3389x; 1.1042x over previous
//
#include <hip/hip_runtime.h>
#include <hip/hip_bf16.h>

constexpr int Bn = 16, Cn = 24, Sn = 128, En = 256, Hn = 8, Pn = 32;
constexpr int NROWS = Bn * Cn * Sn;                  // 49152
constexpr size_t NBUF = (size_t)Bn * Cn * Sn * En;   // 12,582,912 elems
constexpr size_t WSLOT = (size_t)Cn * 256 * 256;     // 1,572,864

typedef __bf16 bf16_t;
typedef bf16_t bf16x8 __attribute__((ext_vector_type(8)));
typedef bf16_t bf16x4 __attribute__((ext_vector_type(4)));
typedef float f32x4 __attribute__((ext_vector_type(4)));

// global -> LDS direct 16B copy (dest = wave-uniform base + lane*16)
__device__ __forceinline__ void gl2lds16(const bf16_t* g, bf16_t* l) {
    typedef const __attribute__((address_space(1))) unsigned int* gp_t;
    typedef __attribute__((address_space(3))) unsigned int* lp_t;
    __builtin_amdgcn_global_load_lds((gp_t)(unsigned long long)g,
                                     (lp_t)(unsigned int)(unsigned long long)l,
                                     16, 0, 0);
}

// ---------------------------------------------------------------------------
// x fp32 -> bf16
// ---------------------------------------------------------------------------
__global__ __launch_bounds__(256) void conv_x_k(const float* __restrict__ x,
                                                bf16_t* __restrict__ xb) {
    const size_t i = ((size_t)blockIdx.x * 256 + threadIdx.x) * 4;
    const float4 v = *(const float4*)(x + i);
    bf16x4 o = {(bf16_t)v.x, (bf16_t)v.y, (bf16_t)v.z, (bf16_t)v.w};
    *(bf16x4*)(xb + i) = o;
}

// ---------------------------------------------------------------------------
// Wq_s copy-convert (source already e-contiguous): [h,c,p,e] -> [c][n=h*32+p][e]
// 4 rows/block, 64 lanes/row, float4 reads + bf16x4 writes, both coalesced.
// ---------------------------------------------------------------------------
__global__ __launch_bounds__(256) void conv_w_copy_k(const float* __restrict__ W,
                                                     bf16_t* __restrict__ out) {
    const int row = blockIdx.x * 4 + (threadIdx.x >> 6);   // c*256+n
    const int lane = threadIdx.x & 63;
    const int n = row & 255, c = row >> 8;
    const float* src = W + (size_t)c * (Pn * En) + (size_t)(n >> 5) * (Cn * Pn * En) +
                       (size_t)(n & 31) * En + lane * 4;
    const float4 v = *(const float4*)src;
    bf16x4 o = {(bf16_t)v.x, (bf16_t)v.y, (bf16_t)v.z, (bf16_t)v.w};
    *(bf16x4*)(out + (size_t)row * 256 + lane * 4) = o;
}

// ---------------------------------------------------------------------------
// Transpose-convert for the 7 e-strided weights -> canonical [slot][c][n][e].
// Source form: addr = c*Sc + g*Snh + e*Se + j   (j = n&31 contiguous, g = n>>5)
// Tile: 64 e x 32 j through padded LDS; reads 128B-coalesced along j,
// writes 16B bf16 chunks contiguous along e.
// grid: x = (etile<<3)|g, y = c, z = slot
// ---------------------------------------------------------------------------
struct TDesc { const float* W; int Sc, Snh, Se; };

__global__ __launch_bounds__(256) void conv_w_tr_k(
    TDesc d0, TDesc d1, TDesc d2, TDesc d3, TDesc d4, TDesc d5, TDesc d6,
    bf16_t* __restrict__ out)
{
    TDesc d;
    switch (blockIdx.z) {
        case 0: d = d0; break; case 1: d = d1; break; case 2: d = d2; break;
        case 3: d = d3; break; case 4: d = d4; break; case 5: d = d5; break;
        default: d = d6; break;
    }
    const int g = blockIdx.x & 7, et = blockIdx.x >> 3;
    const int c = blockIdx.y;

    __shared__ float tile[32][65];

    const int t = threadIdx.x;
    const float* base = d.W + (size_t)c * d.Sc + (size_t)g * d.Snh;

#pragma unroll
    for (int pass = 0; pass < 2; ++pass) {
        const int e_local = pass * 32 + (t >> 3);
        const int j4 = (t & 7) * 4;
        const float4 v = *(const float4*)(base + (size_t)(et * 64 + e_local) * d.Se + j4);
        tile[j4 + 0][e_local] = v.x;
        tile[j4 + 1][e_local] = v.y;
        tile[j4 + 2][e_local] = v.z;
        tile[j4 + 3][e_local] = v.w;
    }
    __syncthreads();

    const int j = t >> 3, e8 = (t & 7) * 8;
    bf16x8 o;
#pragma unroll
    for (int k = 0; k < 8; ++k) o[k] = (bf16_t)tile[j][e8 + k];
    out[(size_t)blockIdx.z * WSLOT + ((size_t)c * 256 + g * 32 + j) * 256 +
        et * 64 + e8] = o[0],  // dummy to keep indices clear -- replaced below
    *(bf16x8*)(out + (size_t)blockIdx.z * WSLOT +
               ((size_t)c * 256 + g * 32 + j) * 256 + et * 64 + e8) = o;
}

// small shared spatial k/v weights (tiny: 64 KB each)
__global__ __launch_bounds__(256) void conv_w_k(const float* __restrict__ W,
                                                bf16_t* __restrict__ Wb,
                                                int Sc, int Snh, int Snp, int Se) {
    const int n = blockIdx.x & 255, c = blockIdx.x >> 8;
    const int e = threadIdx.x;
    Wb[(size_t)blockIdx.x * 256 + e] =
        (bf16_t)W[(size_t)c * Sc + (size_t)(n >> 5) * Snh + (n & 31) * Snp + (size_t)e * Se];
}

// ---------------------------------------------------------------------------
// bf16 MFMA GEMM, up to 3 fused projections sharing A, LDS-staged epilogue.
// trans=0: output n-inner (Onp==1, 32-groups via Onh); stage [m][136].
// trans=1: output m-inner (Os==1); stage [n][136], 16B stores along m.
// EPI: 0 / 1 (bias+relu) / 2 (bias)  (trans=0 path only)
// ---------------------------------------------------------------------------
struct GDesc { const bf16_t* W; bf16_t* O; int Wc, Ob, Oc, Os, Onh, Onp, trans; };

template <int NP, int EPI>
__global__ __launch_bounds__(256) void gemm_mfma(
    const bf16_t* __restrict__ A, int Ab, int Ac, int As,
    GDesc g0, GDesc g1, GDesc g2, const float* __restrict__ bias)
{
    const int b = blockIdx.x, c = blockIdx.z;
    const int proj = (NP == 1) ? 0 : ((int)blockIdx.y >> 1);
    const int nt = (NP == 1) ? (int)blockIdx.y : ((int)blockIdx.y & 1);
    GDesc g = (proj == 0) ? g0 : (proj == 1) ? g1 : g2;

    __shared__ bf16_t As_lds[128 * 32];
    __shared__ bf16_t Bs_lds[128 * 32];
    __shared__ bf16_t Cs[64 * 136];      // epilogue staging (17408 B)

    const int tid = threadIdx.x, wv = tid >> 6, ln = tid & 63;
    const int wm = (wv >> 1) * 64, wn = (wv & 1) * 64;
    const int lr = ln & 15, hi = ln >> 4, lk = hi * 8;

    const bf16_t* Abase = A + (size_t)b * Ab + (size_t)c * Ac;
    const bf16_t* Bbase = g.W + (size_t)c * g.Wc + (size_t)(nt * 128) * 256;

    f32x4 acc[4][4] = {};

    for (int k0 = 0; k0 < 256; k0 += 32) {
#pragma unroll
        for (int it = 0; it < 2; ++it) {
            const int cb = it * 256 + wv * 64;
            const int mc = cb + ln;
            const int row = mc >> 2, kc = (mc & 3) * 8;
            gl2lds16(Abase + (size_t)row * As + k0 + kc, &As_lds[cb * 8]);
            gl2lds16(Bbase + (size_t)row * 256 + k0 + kc, &Bs_lds[cb * 8]);
        }
        __syncthreads();

        bf16x8 af[4], bfr[4];
#pragma unroll
        for (int i = 0; i < 4; ++i)
            af[i] = *(const bf16x8*)&As_lds[(wm + i * 16 + lr) * 32 + lk];
#pragma unroll
        for (int j = 0; j < 4; ++j)
            bfr[j] = *(const bf16x8*)&Bs_lds[(wn + j * 16 + lr) * 32 + lk];
#pragma unroll
        for (int i = 0; i < 4; ++i)
#pragma unroll
            for (int j = 0; j < 4; ++j)
                acc[i][j] = __builtin_amdgcn_mfma_f32_16x16x32_bf16(af[i], bfr[j], acc[i][j], 0, 0, 0);
        __syncthreads();
    }

    // ---- LDS-staged epilogue ----
#pragma unroll
    for (int pass = 0; pass < 2; ++pass) {
        if (!g.trans) {
            if (wm == pass * 64) {
#pragma unroll
                for (int i = 0; i < 4; ++i)
#pragma unroll
                    for (int j = 0; j < 4; ++j) {
                        const int n = nt * 128 + wn + j * 16 + lr;
                        float bv = 0.f;
                        if (EPI) bv = bias[c * 256 + n];
#pragma unroll
                        for (int r = 0; r < 4; ++r) {
                            float v = acc[i][j][r];
                            if (EPI) { v += bv; if (EPI == 1) v = fmaxf(v, 0.f); }
                            Cs[(i * 16 + hi * 4 + r) * 136 + wn + j * 16 + lr] = (bf16_t)v;
                        }
                    }
            }
            __syncthreads();
#pragma unroll
            for (int it = 0; it < 2; ++it) {
                const int lrow = it * 32 + (tid >> 3);
                const int n0 = (tid & 7) * 16;
                bf16x8 v0 = *(const bf16x8*)&Cs[lrow * 136 + n0];
                bf16x8 v1 = *(const bf16x8*)&Cs[lrow * 136 + n0 + 8];
                const int m = pass * 64 + lrow;
                const int n = nt * 128 + n0;
                bf16_t* dst = g.O + (size_t)b * g.Ob + (size_t)c * g.Oc +
                              (size_t)m * g.Os + (size_t)(n >> 5) * g.Onh + (n & 31);
                *(bf16x8*)dst = v0;
                *(bf16x8*)(dst + 8) = v1;
            }
            __syncthreads();
        } else {
            if (wn == pass * 64) {
#pragma unroll
                for (int i = 0; i < 4; ++i)
#pragma unroll
                    for (int j = 0; j < 4; ++j) {
                        bf16x4 pk = {(bf16_t)acc[i][j][0], (bf16_t)acc[i][j][1],
                                     (bf16_t)acc[i][j][2], (bf16_t)acc[i][j][3]};
                        *(bf16x4*)&Cs[(j * 16 + lr) * 136 + wm + i * 16 + hi * 4] = pk;
                    }
            }
            __syncthreads();
#pragma unroll
            for (int it = 0; it < 2; ++it) {
                const int lrow = it * 32 + (tid >> 3);
                const int m0 = (tid & 7) * 16;
                bf16x8 v0 = *(const bf16x8*)&Cs[lrow * 136 + m0];
                bf16x8 v1 = *(const bf16x8*)&Cs[lrow * 136 + m0 + 8];
                const int n = nt * 128 + pass * 64 + lrow;
                bf16_t* dst = g.O + (size_t)b * g.Ob + (size_t)c * g.Oc +
                              (size_t)(n >> 5) * g.Onh + (size_t)(n & 31) * g.Onp + m0;
                *(bf16x8*)dst = v0;
                *(bf16x8*)(dst + 8) = v1;
            }
            __syncthreads();
        }
    }
}

// ---------------------------------------------------------------------------
// Spatial attention, MFMA, one wave per (b,s,h). 24x24 padded to 32.
// ---------------------------------------------------------------------------
__global__ __launch_bounds__(256) void attn_spatial_mfma(
    const bf16_t* __restrict__ Q, const bf16_t* __restrict__ K,
    const bf16_t* __restrict__ V, bf16_t* __restrict__ O)
{
    __shared__ bf16_t Ps[4][32 * 40];
    __shared__ bf16_t Vt[4][32 * 40];

    const int tid = threadIdx.x, wv = tid >> 6, ln = tid & 63;
    const int lr = ln & 15, hi = ln >> 4, lk = hi * 8;

    const int bsh = blockIdx.x * 4 + wv;
    const int h = bsh & 7, s = (bsh >> 3) & 127, b = bsh >> 10;
    const size_t qb = (size_t)bsh * (Cn * Pn);

    {
        const int p = ln >> 1, c0 = 24 + (ln & 1) * 4;
        bf16x4 z = {};
        *(bf16x4*)&Vt[wv][p * 40 + c0] = z;
    }
#pragma unroll
    for (int it = 0; it < 2; ++it) {
        const int ch = it * 64 + ln;
        if (ch < 96) {
            const int cc = ch >> 2, p0 = (ch & 3) * 8;
            bf16x8 v = *(const bf16x8*)(V + qb + cc * 32 + p0);
#pragma unroll
            for (int j = 0; j < 8; ++j)
                Vt[wv][(p0 + j) * 40 + cc] = v[j];
        }
    }

    bf16x8 aq0 = *(const bf16x8*)(Q + qb + lr * 32 + lk);
    bf16x8 aq1 = *(const bf16x8*)(Q + qb + (16 + lr) * 32 + lk);
    bf16x8 bk0 = *(const bf16x8*)(K + qb + lr * 32 + lk);
    bf16x8 bk1 = *(const bf16x8*)(K + qb + (16 + lr) * 32 + lk);
    const f32x4 zz = {0.f, 0.f, 0.f, 0.f};
    f32x4 sc[2][2];
    sc[0][0] = __builtin_amdgcn_mfma_f32_16x16x32_bf16(aq0, bk0, zz, 0, 0, 0);
    sc[0][1] = __builtin_amdgcn_mfma_f32_16x16x32_bf16(aq0, bk1, zz, 0, 0, 0);
    sc[1][0] = __builtin_amdgcn_mfma_f32_16x16x32_bf16(aq1, bk0, zz, 0, 0, 0);
    sc[1][1] = __builtin_amdgcn_mfma_f32_16x16x32_bf16(aq1, bk1, zz, 0, 0, 0);

    const float scale = 0.17677669529663687f;
#pragma unroll
    for (int i = 0; i < 2; ++i) {
        float s0[4], s1[4], mx[4];
#pragma unroll
        for (int r = 0; r < 4; ++r) {
            s0[r] = sc[i][0][r] * scale;
            s1[r] = (lr >= 8) ? -3.0e38f : sc[i][1][r] * scale;
            mx[r] = fmaxf(s0[r], s1[r]);
        }
#pragma unroll
        for (int d = 1; d < 16; d <<= 1)
#pragma unroll
            for (int r = 0; r < 4; ++r) mx[r] = fmaxf(mx[r], __shfl_xor(mx[r], d));
        float e0[4], e1[4], sm[4];
#pragma unroll
        for (int r = 0; r < 4; ++r) {
            e0[r] = __expf(s0[r] - mx[r]);
            e1[r] = __expf(s1[r] - mx[r]);
            sm[r] = e0[r] + e1[r];
        }
#pragma unroll
        for (int d = 1; d < 16; d <<= 1)
#pragma unroll
            for (int r = 0; r < 4; ++r) sm[r] += __shfl_xor(sm[r], d);
#pragma unroll
        for (int r = 0; r < 4; ++r) {
            const float inv = 1.f / sm[r];
            const int row = i * 16 + hi * 4 + r;
            Ps[wv][row * 40 + lr]      = (bf16_t)(e0[r] * inv);
            Ps[wv][row * 40 + 16 + lr] = (bf16_t)(e1[r] * inv);
        }
    }

    bf16x8 ap0 = *(const bf16x8*)&Ps[wv][lr * 40 + lk];
    bf16x8 ap1 = *(const bf16x8*)&Ps[wv][(16 + lr) * 40 + lk];
    bf16x8 bv0 = *(const bf16x8*)&Vt[wv][lr * 40 + lk];
    bf16x8 bv1 = *(const bf16x8*)&Vt[wv][(16 + lr) * 40 + lk];
    f32x4 o[2][2];
    o[0][0] = __builtin_amdgcn_mfma_f32_16x16x32_bf16(ap0, bv0, zz, 0, 0, 0);
    o[0][1] = __builtin_amdgcn_mfma_f32_16x16x32_bf16(ap0, bv1, zz, 0, 0, 0);
    o[1][0] = __builtin_amdgcn_mfma_f32_16x16x32_bf16(ap1, bv0, zz, 0, 0, 0);
    o[1][1] = __builtin_amdgcn_mfma_f32_16x16x32_bf16(ap1, bv1, zz, 0, 0, 0);

#pragma unroll
    for (int i = 0; i < 2; ++i)
#pragma unroll
        for (int r = 0; r < 4; ++r) {
            const int c = i * 16 + hi * 4 + r;
            if (c < 24) {
                const size_t ob = ((size_t)(b * Cn + c) * Sn + s) * En + h * Pn;
#pragma unroll
                for (int j = 0; j < 2; ++j)
                    O[ob + j * 16 + lr] = (bf16_t)o[i][j][r];
            }
        }
}

// ---------------------------------------------------------------------------
// Temporal attention, MFMA. One block (4 waves) per (b,h,c).
// ---------------------------------------------------------------------------
__global__ __launch_bounds__(256) void attn_temporal_mfma(
    const bf16_t* __restrict__ Q, const bf16_t* __restrict__ K,
    const bf16_t* __restrict__ Vt, bf16_t* __restrict__ O)
{
    const int c = blockIdx.x, h = blockIdx.y, b = blockIdx.z;
    const size_t base = ((size_t)(b * Hn + h) * Cn + c) * (Sn * Pn);

    __shared__ bf16_t Qs[128 * 32];
    __shared__ bf16_t Ks[128 * 32];
    __shared__ bf16_t Vs[32 * 136];
    __shared__ bf16_t Ps[128 * 136];

    const int tid = threadIdx.x, wv = tid >> 6, ln = tid & 63;
    const int lr = ln & 15, lk = (ln >> 4) * 8;

#pragma unroll
    for (int it = 0; it < 2; ++it) {
        const int cb = it * 256 + wv * 64;
        const int mc = cb + ln;
        const int row = mc >> 2, kc = (mc & 3) * 8;
        gl2lds16(Q + base + row * 32 + kc, &Qs[cb * 8]);
        gl2lds16(K + base + row * 32 + kc, &Ks[cb * 8]);
    }
#pragma unroll
    for (int it = 0; it < 2; ++it) {
        const int mc = it * 256 + tid;
        const int p = mc >> 4, scn = (mc & 15) * 8;
        bf16x8 v = *(const bf16x8*)(Vt + base + p * 128 + scn);
        *(bf16x8*)&Vs[p * 136 + scn] = v;
    }
    __syncthreads();

    const int r0 = wv * 32;
    bf16x8 aq0 = *(const bf16x8*)&Qs[(r0 + lr) * 32 + lk];
    bf16x8 aq1 = *(const bf16x8*)&Qs[(r0 + 16 + lr) * 32 + lk];
    f32x4 sc_[2][8];
    const f32x4 zz = {0.f, 0.f, 0.f, 0.f};
#pragma unroll
    for (int j = 0; j < 8; ++j) {
        bf16x8 bk = *(const bf16x8*)&Ks[(j * 16 + lr) * 32 + lk];
        sc_[0][j] = __builtin_amdgcn_mfma_f32_16x16x32_bf16(aq0, bk, zz, 0, 0, 0);
        sc_[1][j] = __builtin_amdgcn_mfma_f32_16x16x32_bf16(aq1, bk, zz, 0, 0, 0);
    }

    const float scale = 0.17677669529663687f;
#pragma unroll
    for (int i = 0; i < 2; ++i) {
        float mx[4], sm[4];
#pragma unroll
        for (int r = 0; r < 4; ++r) {
            float m = sc_[i][0][r];
#pragma unroll
            for (int j = 1; j < 8; ++j) m = fmaxf(m, sc_[i][j][r]);
            mx[r] = m;
        }
#pragma unroll
        for (int d = 1; d < 16; d <<= 1)
#pragma unroll
            for (int r = 0; r < 4; ++r) mx[r] = fmaxf(mx[r], __shfl_xor(mx[r], d));
#pragma unroll
        for (int r = 0; r < 4; ++r) sm[r] = 0.f;
#pragma unroll
        for (int j = 0; j < 8; ++j)
#pragma unroll
            for (int r = 0; r < 4; ++r) {
                const float e = __expf((sc_[i][j][r] - mx[r]) * scale);
                sc_[i][j][r] = e; sm[r] += e;
            }
#pragma unroll
        for (int d = 1; d < 16; d <<= 1)
#pragma unroll
            for (int r = 0; r < 4; ++r) sm[r] += __shfl_xor(sm[r], d);
        float inv[4];
#pragma unroll
        for (int r = 0; r < 4; ++r) inv[r] = 1.f / sm[r];
        const int rb = r0 + i * 16 + (ln >> 4) * 4;
#pragma unroll
        for (int j = 0; j < 8; ++j)
#pragma unroll
            for (int r = 0; r < 4; ++r)
                Ps[(rb + r) * 136 + j * 16 + lr] = (bf16_t)(sc_[i][j][r] * inv[r]);
    }
    __syncthreads();

    f32x4 o[2][2] = {};
#pragma unroll
    for (int kk = 0; kk < 4; ++kk) {
        bf16x8 ap0 = *(const bf16x8*)&Ps[(r0 + lr) * 136 + kk * 32 + lk];
        bf16x8 ap1 = *(const bf16x8*)&Ps[(r0 + 16 + lr) * 136 + kk * 32 + lk];
        bf16x8 bv0 = *(const bf16x8*)&Vs[lr * 136 + kk * 32 + lk];
        bf16x8 bv1 = *(const bf16x8*)&Vs[(16 + lr) * 136 + kk * 32 + lk];
        o[0][0] = __builtin_amdgcn_mfma_f32_16x16x32_bf16(ap0, bv0, o[0][0], 0, 0, 0);
        o[0][1] = __builtin_amdgcn_mfma_f32_16x16x32_bf16(ap0, bv1, o[0][1], 0, 0, 0);
        o[1][0] = __builtin_amdgcn_mfma_f32_16x16x32_bf16(ap1, bv0, o[1][0], 0, 0, 0);
        o[1][1] = __builtin_amdgcn_mfma_f32_16x16x32_bf16(ap1, bv1, o[1][1], 0, 0, 0);
    }

#pragma unroll
    for (int i = 0; i < 2; ++i) {
        const int sb = r0 + i * 16 + (ln >> 4) * 4;
#pragma unroll
        for (int j = 0; j < 2; ++j) {
            const int p = h * 32 + j * 16 + lr;
#pragma unroll
            for (int r = 0; r < 4; ++r)
                O[((size_t)(b * Cn + c) * Sn + (sb + r)) * En + p] = (bf16_t)o[i][j][r];
        }
    }
}

// ---------------------------------------------------------------------------
// attn_out = LN(xb + spat) + LN(xb + temp)
// ---------------------------------------------------------------------------
__global__ __launch_bounds__(256) void ln_combine_k(
    const bf16_t* __restrict__ xb, const bf16_t* __restrict__ spat,
    const bf16_t* __restrict__ temp, const float* __restrict__ g,
    const float* __restrict__ beta, bf16_t* __restrict__ AO)
{
    const int row = blockIdx.x * 4 + (threadIdx.x >> 6);
    const int lane = threadIdx.x & 63;
    const size_t off = (size_t)row * En;

    float v1[4], v2[4];
    float s1 = 0, s2 = 0, q1 = 0, q2 = 0;
#pragma unroll
    for (int i = 0; i < 4; i++) {
        const int e = lane + i * 64;
        const float xv = (float)xb[off + e];
        const float a = xv + (float)spat[off + e];
        const float t = xv + (float)temp[off + e];
        v1[i] = a; v2[i] = t;
        s1 += a; s2 += t; q1 += a * a; q2 += t * t;
    }
    for (int d = 32; d; d >>= 1) {
        s1 += __shfl_xor(s1, d); s2 += __shfl_xor(s2, d);
        q1 += __shfl_xor(q1, d); q2 += __shfl_xor(q2, d);
    }
    const float mu1 = s1 / En, mu2 = s2 / En;
    const float r1 = rsqrtf(q1 / En - mu1 * mu1 + 1e-6f);
    const float r2 = rsqrtf(q2 / En - mu2 * mu2 + 1e-6f);
#pragma unroll
    for (int i = 0; i < 4; i++) {
        const int e = lane + i * 64;
        const float out = (v1[i] - mu1) * r1 * g[e] + beta[e] +
                          (v2[i] - mu2) * r2 * g[e] + beta[e];
        AO[off + e] = (bf16_t)out;
    }
}

__global__ __launch_bounds__(256) void ln_final_k(
    const bf16_t* __restrict__ AO, const bf16_t* __restrict__ FF,
    const float* __restrict__ g, const float* __restrict__ beta,
    float* __restrict__ out)
{
    const int row = blockIdx.x * 4 + (threadIdx.x >> 6);
    const int lane = threadIdx.x & 63;
    const size_t off = (size_t)row * En;

    float v[4];
    float s = 0, q = 0;
#pragma unroll
    for (int i = 0; i < 4; i++) {
        const int e = lane + i * 64;
        const float a = (float)AO[off + e] + (float)FF[off + e];
        v[i] = a; s += a; q += a * a;
    }
    for (int d = 32; d; d >>= 1) { s += __shfl_xor(s, d); q += __shfl_xor(q, d); }
    const float mu = s / En;
    const float r = rsqrtf(q / En - mu * mu + 1e-6f);
#pragma unroll
    for (int i = 0; i < 4; i++) {
        const int e = lane + i * 64;
        out[off + e] = (v[i] - mu) * r * g[e] + beta[e];
    }
}

// ---------------------------------------------------------------------------
extern "C" void kernel_launch(void* const* d_in, const int* in_sizes, int n_in,
                              void* d_out, int out_size, void* d_ws, size_t ws_size,
                              hipStream_t stream)
{
    const float* x     = (const float*)d_in[0];
    const float* Wq_s  = (const float*)d_in[1];
    const float* Wk_s  = (const float*)d_in[2];
    const float* Wv_s  = (const float*)d_in[3];
    const float* Wo_s  = (const float*)d_in[4];
    const float* Wq_t  = (const float*)d_in[5];
    const float* Wk_t  = (const float*)d_in[6];
    const float* Wv_t  = (const float*)d_in[7];
    const float* Wo_t  = (const float*)d_in[8];
    const float* ln_g  = (const float*)d_in[9];
    const float* ln_b  = (const float*)d_in[10];
    const float* ff_w1 = (const float*)d_in[11];
    const float* ff_b1 = (const float*)d_in[12];
    const float* ff_w2 = (const float*)d_in[13];
    const float* ff_b2 = (const float*)d_in[14];
    float* out = (float*)d_out;

    bf16_t* wsb = (bf16_t*)d_ws;
    bf16_t* b0 = wsb;
    bf16_t* b1 = wsb + NBUF;
    bf16_t* b2 = wsb + 2 * NBUF;
    bf16_t* b3 = wsb + 3 * NBUF;
    bf16_t* b4 = wsb + 4 * NBUF;

    // d_out doubles as scratch: xb + 8 canonical weight slots
    bf16_t* xb = (bf16_t*)d_out;
    bf16_t* wb = xb + NBUF;
    bf16_t* w_qs = wb + 0 * WSLOT;      // copy-convert slot
    bf16_t* wtr  = wb + 1 * WSLOT;      // 7 transpose slots follow
    bf16_t* w_os = wtr + 0 * WSLOT;
    bf16_t* w_qt = wtr + 1 * WSLOT;
    bf16_t* w_kt = wtr + 2 * WSLOT;
    bf16_t* w_vt = wtr + 3 * WSLOT;
    bf16_t* w_ot = wtr + 4 * WSLOT;
    bf16_t* w_f1 = wtr + 5 * WSLOT;
    bf16_t* w_f2 = wtr + 6 * WSLOT;
    bf16_t* w_ks = b4 + NBUF - 2 * 65536;   // b4 first written after these die
    bf16_t* w_vs = b4 + NBUF - 65536;

    // strides
    const int XAb = Cn * Sn * En, XAc = Sn * En, XAs = En;                          // [B,C,S,E]
    const int QSb = Sn * Hn * Cn * Pn, QSs = Hn * Cn * Pn, QSh = Cn * Pn;           // [B,S,H,C,P]
    const int QTb = Hn * Cn * Sn * Pn, QTh = Cn * Sn * Pn, QTc = Sn * Pn, QTs = Pn; // [B,H,C,S,P]
    const int WCP = 256 * 256;

    // --- conversions (source-major, coalesced) ---
    conv_x_k<<<NBUF / 1024, 256, 0, stream>>>(x, xb);
    conv_w_copy_k<<<1536, 256, 0, stream>>>(Wq_s, w_qs);
    conv_w_tr_k<<<dim3(32, 24, 7), 256, 0, stream>>>(
        TDesc{Wo_s, En * En, Pn, En},                 // [c,e,f]: g=f>>5
        TDesc{Wq_t, En * Pn, Cn * En * Pn, Pn},       // [h,c,e,p]: g=h
        TDesc{Wk_t, En * Pn, Cn * En * Pn, Pn},
        TDesc{Wv_t, En * Pn, Cn * En * Pn, Pn},
        TDesc{Wo_t, En * En, Pn, En},
        TDesc{ff_w1, En * En, Pn, En},
        TDesc{ff_w2, En * En, Pn, En},
        wtr);
    conv_w_k<<<256, 256, 0, stream>>>(Wk_s, w_ks, 0, En * Pn, 1, Pn);
    conv_w_k<<<256, 256, 0, stream>>>(Wv_s, w_vs, 0, En * Pn, 1, Pn);

    // --- spatial branch: fused QKV, all [B,S,H,C,P] (V transposed in-kernel) ---
    gemm_mfma<3, 0><<<dim3(16, 6, 24), 256, 0, stream>>>(
        xb, XAb, XAc, XAs,
        GDesc{w_qs, b0, WCP, QSb, Pn, QSs, QSh, 1, 0},
        GDesc{w_ks, b1, 0,   QSb, Pn, QSs, QSh, 1, 0},
        GDesc{w_vs, b2, 0,   QSb, Pn, QSs, QSh, 1, 0},
        nullptr);
    attn_spatial_mfma<<<Bn * Sn * Hn / 4, 256, 0, stream>>>(b0, b1, b2, b3);
    gemm_mfma<1, 0><<<dim3(16, 2, 24), 256, 0, stream>>>(
        b3, XAb, XAc, XAs,
        GDesc{w_os, b4, WCP, XAb, XAc, XAs, 32, 1, 0},
        GDesc{w_os, b4, WCP, XAb, XAc, XAs, 32, 1, 0},
        GDesc{w_os, b4, WCP, XAb, XAc, XAs, 32, 1, 0}, nullptr);

    // --- temporal branch: fused QKV (V pre-transposed [b,h,c,p,s] via trans=1) ---
    gemm_mfma<3, 0><<<dim3(16, 6, 24), 256, 0, stream>>>(
        xb, XAb, XAc, XAs,
        GDesc{w_qt, b0, WCP, QTb, QTc, QTs, QTh, 1, 0},
        GDesc{w_kt, b1, WCP, QTb, QTc, QTs, QTh, 1, 0},
        GDesc{w_vt, b2, WCP, QTb, QTc, 1, QTh, Sn, 1},
        nullptr);
    attn_temporal_mfma<<<dim3(24, 8, 16), 256, 0, stream>>>(b0, b1, b2, b3);
    gemm_mfma<1, 0><<<dim3(16, 2, 24), 256, 0, stream>>>(
        b3, XAb, XAc, XAs,
        GDesc{w_ot, b0, WCP, XAb, XAc, XAs, 32, 1, 0},
        GDesc{w_ot, b0, WCP, XAb, XAc, XAs, 32, 1, 0},
        GDesc{w_ot, b0, WCP, XAb, XAc, XAs, 32, 1, 0}, nullptr);

    // --- combine + FF + final LN ---
    ln_combine_k<<<NROWS / 4, 256, 0, stream>>>(xb, b4, b0, ln_g, ln_b, b1);
    gemm_mfma<1, 1><<<dim3(16, 2, 24), 256, 0, stream>>>(
        b1, XAb, XAc, XAs,
        GDesc{w_f1, b2, WCP, XAb, XAc, XAs, 32, 1, 0},
        GDesc{w_f1, b2, WCP, XAb, XAc, XAs, 32, 1, 0},
        GDesc{w_f1, b2, WCP, XAb, XAc, XAs, 32, 1, 0}, ff_b1);
    gemm_mfma<1, 2><<<dim3(16, 2, 24), 256, 0, stream>>>(
        b2, XAb, XAc, XAs,
        GDesc{w_f2, b3, WCP, XAb, XAc, XAs, 32, 1, 0},
        GDesc{w_f2, b3, WCP, XAb, XAc, XAs, 32, 1, 0},
        GDesc{w_f2, b3, WCP, XAb, XAc, XAs, 32, 1, 0}, ff_b2);
    ln_final_k<<<NROWS / 4, 256, 0, stream>>>(b1, b3, ln_g, ln_b, out);
}